// Round 1
// 368.268 us; speedup vs baseline: 1.0703x; 1.0703x over previous
//
#include <hip/hip_runtime.h>
#include <math.h>

// Problem constants: B=2, N=2048, D=1024, H=16, HD=64, C=4

typedef __attribute__((ext_vector_type(8))) short s8v;
typedef __attribute__((ext_vector_type(4))) short s4v;
typedef __attribute__((ext_vector_type(4))) float f4v;

#define L2E 1.44269504088896340736f

__device__ __forceinline__ unsigned short f2bf(float x) {
    union { float f; unsigned u; } v; v.f = x;
    unsigned r = v.u + 0x7FFF + ((v.u >> 16) & 1);
    return (unsigned short)(r >> 16);
}
__device__ __forceinline__ float bf2f(unsigned short h) {
    union { unsigned u; float f; } v; v.u = ((unsigned)h) << 16;
    return v.f;
}
__device__ __forceinline__ f4v mfma32(s8v a, s8v b, f4v c) {
    return __builtin_amdgcn_mfma_f32_16x16x32_bf16(a, b, c, 0, 0, 0);
}
__device__ __forceinline__ f4v mfma16x16(s4v a, s4v b, f4v c) {
    return __builtin_amdgcn_mfma_f32_16x16x16bf16_1k(a, b, c, 0, 0, 0);
}
__device__ __forceinline__ void gl_lds16(const void* g, void* l) {
    __builtin_amdgcn_global_load_lds(
        (const __attribute__((address_space(1))) unsigned*)g,
        (__attribute__((address_space(3))) unsigned*)l, 16, 0, 0);
}
// raw v_exp_f32: 1 instr, no OCML range-fixup wrapper
__device__ __forceinline__ float exp2g(float x) {
    float r; asm("v_exp_f32 %0, %1" : "=v"(r) : "v"(x)); return r;
}

// ---------------------------------------------------------------------------
// Split fp32 tensor into bf16 hi/lo planes.
// ---------------------------------------------------------------------------
__global__ __launch_bounds__(256)
void planes_k(const float* __restrict__ src, short* __restrict__ ph,
              short* __restrict__ pl)
{
    const int i = blockIdx.x * 256 + threadIdx.x;
    float4 f = ((const float4*)src)[i];
    float fa[4] = {f.x, f.y, f.z, f.w};
    s4v h4, l4;
#pragma unroll
    for (int j = 0; j < 4; j++) {
        unsigned short hb = f2bf(fa[j]);
        h4[j] = (short)hb;
        l4[j] = (short)f2bf(fa[j] - bf2f(hb));
    }
    ((s4v*)ph)[i] = h4;
    ((s4v*)pl)[i] = l4;
}

// ---------------------------------------------------------------------------
// MFMA GEMM  C[M,NC] = A[M,1024] * B[NC,1024]^T from bf16 hi/lo planes.
// 3-term split.  Tile TM x 128, BK=32.
// MODE 0 (TM=128): fused RMSNorm (q/k; q pre-scaled by 0.125*log2(e)) +
//                  scatter -> q/k hi/lo planes, v written TRANSPOSED
//                  (V^T[b,h,d,n], bf16, vectorized s4v stores).
// MODE 1 (TM=64):  plain fp32 row-major Cout.
// ---------------------------------------------------------------------------
template<int MODE, int TM>
__global__ __launch_bounds__(256, 3)
void gemm_mfma(const short* __restrict__ Ah, const short* __restrict__ Al,
               const short* __restrict__ Bh, const short* __restrict__ Bl,
               short* __restrict__ Qhp, short* __restrict__ Qlp,
               short* __restrict__ Khp, short* __restrict__ Klp,
               short* __restrict__ Vp, float* __restrict__ Cout,
               const float* __restrict__ qw, const float* __restrict__ kw)
{
    constexpr int MJ = (TM == 128) ? 4 : 2;
    constexpr int JW = (TM == 128) ? 64 : 32;
    __shared__ short sAh[TM*32], sAl[TM*32], sBh[128*32], sBl[128*32];

    const int t = threadIdx.x, w = t >> 6, lane = t & 63;
    const int col = lane & 15, quad = lane >> 4;
    const int wm = (TM == 128) ? (w >> 1) : 0;
    const int wn = (TM == 128) ? (w & 1) : w;
    const int m0 = blockIdx.y * TM, n0 = blockIdx.x * 128;

    f4v acc[4][MJ];
#pragma unroll
    for (int i = 0; i < 4; i++)
#pragma unroll
        for (int j = 0; j < MJ; j++) { f4v z = {0.f,0.f,0.f,0.f}; acc[i][j] = z; }

    const int r4 = lane >> 2;
    const int cs = ((lane & 3) ^ (r4 & 3)) * 8;
    const short* agh = Ah + (size_t)(m0 + w*16 + r4)*1024 + cs;
    const short* agl = Al + (size_t)(m0 + w*16 + r4)*1024 + cs;
    const short* bgh = Bh + (size_t)(n0 + w*16 + r4)*1024 + cs;
    const short* bgl = Bl + (size_t)(n0 + w*16 + r4)*1024 + cs;

    for (int kt = 0; kt < 32; kt++) {
        const int k0 = kt * 32;
        __syncthreads();
#pragma unroll
        for (int j = 0; j < TM/64; j++) {
            gl_lds16(agh + k0 + j*65536, &sAh[(j*4 + w)*512]);
            gl_lds16(agl + k0 + j*65536, &sAl[(j*4 + w)*512]);
        }
#pragma unroll
        for (int j = 0; j < 2; j++) {
            gl_lds16(bgh + k0 + j*65536, &sBh[(j*4 + w)*512]);
            gl_lds16(bgl + k0 + j*65536, &sBl[(j*4 + w)*512]);
        }
        __syncthreads();

        const int swz = ((quad ^ (col & 3)) << 3);
        s8v ahf[4], alf[4], bhf[MJ], blf[MJ];
#pragma unroll
        for (int i = 0; i < 4; i++) {
            const int aoff = (wm*64 + i*16 + col)*32 + swz;
            ahf[i] = *(const s8v*)&sAh[aoff];
            alf[i] = *(const s8v*)&sAl[aoff];
        }
#pragma unroll
        for (int j = 0; j < MJ; j++) {
            const int boff = (wn*JW + j*16 + col)*32 + swz;
            bhf[j] = *(const s8v*)&sBh[boff];
            blf[j] = *(const s8v*)&sBl[boff];
        }
#pragma unroll
        for (int i = 0; i < 4; i++)
#pragma unroll
        for (int j = 0; j < MJ; j++) {
            acc[i][j] = mfma32(ahf[i], bhf[j], acc[i][j]);
            acc[i][j] = mfma32(ahf[i], blf[j], acc[i][j]);
            acc[i][j] = mfma32(alf[i], bhf[j], acc[i][j]);
        }
    }

    if (MODE == 0) {
        // fused RMSNorm over HD=64; q additionally folded with 0.125*log2(e)
        const int whichW = (n0 + wn*64) >> 10;      // wave-uniform: 0=q,1=k,2=v
        if (whichW < 2) {
            const float* nw = (whichW == 0) ? qw : kw;
            const float sfac = (whichW == 0) ? (0.125f * L2E) : 1.0f;
            float wj[4];
#pragma unroll
            for (int j = 0; j < 4; j++) wj[j] = nw[j*16 + col] * sfac;
#pragma unroll
            for (int i = 0; i < 4; i++)
#pragma unroll
            for (int r = 0; r < 4; r++) {
                float s2 = acc[i][0][r]*acc[i][0][r] + acc[i][1][r]*acc[i][1][r]
                         + acc[i][2][r]*acc[i][2][r] + acc[i][3][r]*acc[i][3][r];
                s2 += __shfl_xor(s2, 1);
                s2 += __shfl_xor(s2, 2);
                s2 += __shfl_xor(s2, 4);
                s2 += __shfl_xor(s2, 8);
                const float scn = rsqrtf(s2*(1.0f/64.0f) + 1e-6f);
#pragma unroll
                for (int j = 0; j < 4; j++) acc[i][j][r] *= scn*wj[j];
            }
        }
    }

    if (MODE == 0) {
#pragma unroll
        for (int i = 0; i < 4; i++)
#pragma unroll
        for (int j = 0; j < MJ; j++) {
            const int gcol = n0 + wn*JW + j*16 + col;
            const int which = gcol >> 10;           // wave-uniform
            const int hh = (gcol >> 6) & 15;
            const int hd = gcol & 63;
            const int grow0 = m0 + wm*64 + i*16 + quad*4;
            const int b = grow0 >> 11, nn0 = grow0 & 2047;
            if (which == 2) {
                // V^T[b,h,d,n] bf16 — 4 consecutive n per thread -> s4v store
                s4v hv;
#pragma unroll
                for (int r = 0; r < 4; r++) hv[r] = (short)f2bf(acc[i][j][r]);
                *(s4v*)&Vp[((size_t)(b*16 + hh)*64 + hd)*2048 + nn0] = hv;
            } else {
                short* Hp = (which == 0) ? Qhp : Khp;
                short* Lp = (which == 0) ? Qlp : Klp;
                const size_t base = ((size_t)(b*16 + hh)*2048 + nn0)*64 + hd;
#pragma unroll
                for (int r = 0; r < 4; r++) {
                    const float v = acc[i][j][r];
                    const unsigned short hb = f2bf(v);
                    union { float f; unsigned u; } rr; rr.f = v - bf2f(hb);
                    Hp[base + (size_t)r*64] = (short)hb;
                    Lp[base + (size_t)r*64] = (short)(rr.u >> 16);
                }
            }
        }
    } else {
#pragma unroll
        for (int i = 0; i < 4; i++)
#pragma unroll
        for (int j = 0; j < MJ; j++) {
            const int gcol = n0 + wn*JW + j*16 + col;
#pragma unroll
            for (int r = 0; r < 4; r++) {
                const int grow = m0 + wm*64 + i*16 + quad*4 + r;
                Cout[(size_t)grow*1024 + gcol] = acc[i][j][r];
            }
        }
    }
}

// ---------------------------------------------------------------------------
// rowscale[b,q] = 1 / max(max_k dot4(cm[b,:,q], cm[b,:,k]), 1e-6)
// ---------------------------------------------------------------------------
__global__ __launch_bounds__(256)
void rowscale_k(const float* __restrict__ cm, float* __restrict__ rs)
{
    __shared__ float cms[4][2048];
    const int b  = blockIdx.x >> 5;
    const int qt = blockIdx.x & 31;
    const float* base = cm + (size_t)b * 4 * 2048;
    for (int i = threadIdx.x; i < 2048; i += 256) {
        cms[0][i] = base[i];
        cms[1][i] = base[2048 + i];
        cms[2][i] = base[4096 + i];
        cms[3][i] = base[6144 + i];
    }
    __syncthreads();
    const int q    = qt * 64 + (threadIdx.x >> 2);
    const int part = threadIdx.x & 3;
    const float a0 = cms[0][q], a1 = cms[1][q], a2 = cms[2][q], a3 = cms[3][q];
    float mx = 0.f;
    for (int i = 0; i < 512; i++) {
        const int k = part + 4 * i;
        float d = a0*cms[0][k] + a1*cms[1][k] + a2*cms[2][k] + a3*cms[3][k];
        mx = fmaxf(mx, d);
    }
    mx = fmaxf(mx, __shfl_xor(mx, 1));
    mx = fmaxf(mx, __shfl_xor(mx, 2));
    if (part == 0) rs[b * 2048 + q] = 1.0f / fmaxf(mx, 1e-6f);
}

// ---------------------------------------------------------------------------
// Bias precompute, pre-scaled by 3*log2(e) (gate applied in attn):
//  Bias2[b][k>>2][q][k&3] = ((dot4*rsq - 0.5)*2 + 0.3*im) * 3*L2E
// ---------------------------------------------------------------------------
__global__ __launch_bounds__(256)
void bias_pre(const float* __restrict__ cm, const float* __restrict__ im,
              const float* __restrict__ rs, float* __restrict__ Bias2)
{
    const int bid = blockIdx.x;
    const int qq = bid & 3;
    const int kt = (bid >> 2) & 31;
    const int b  = bid >> 7;

    __shared__ float cmk[4][64];
    const int t = threadIdx.x;
    const int k0 = kt * 64;
    cmk[t >> 6][t & 63] = cm[(size_t)b*8192 + (t >> 6)*2048 + k0 + (t & 63)];
    __syncthreads();

    const int klane = t & 15;
    const int qrow  = t >> 4;
    const int kk = k0 + klane*4;
    const int kg = kk >> 2;
    float ck[4][4];
#pragma unroll
    for (int c = 0; c < 4; c++)
#pragma unroll
        for (int j = 0; j < 4; j++) ck[c][j] = cmk[c][klane*4 + j];

    const float* cmb = cm + (size_t)b * 8192;
    const float kS = 3.0f * L2E;
    for (int it = 0; it < 32; it++) {
        const int q = qq*512 + it*16 + qrow;
        float4 imv = *(const float4*)(im + ((size_t)b*2048 + q)*2048 + kk);
        const float rsq = rs[b*2048 + q];
        const float c0 = cmb[q], c1 = cmb[2048+q], c2 = cmb[4096+q], c3 = cmb[6144+q];
        float o[4];
        float iv[4] = {imv.x, imv.y, imv.z, imv.w};
#pragma unroll
        for (int j = 0; j < 4; j++) {
            float same = c0*ck[0][j] + c1*ck[1][j] + c2*ck[2][j] + c3*ck[3][j];
            o[j] = ((same*rsq - 0.5f)*2.0f + 0.3f*iv[j]) * kS;
        }
        *(float4*)(Bias2 + (((size_t)b*512 + kg)*2048 + q)*4) =
            make_float4(o[0], o[1], o[2], o[3]);
    }
}

// ---------------------------------------------------------------------------
// Flash attention, S^T orientation.  q-tile 128 (32 q/wave), 512 blocks,
// 2 blocks/CU.  K AND V staged by global_load_lds DMA (double-buffered,
// XOR source swizzle); V arrives pre-transposed (V^T global layout from
// gemm0) so no in-kernel transpose and ONE barrier per tile.  Bias
// double-buffered in registers one tile ahead.  Softmax: folded scales
// (single FMA), raw v_exp_f32, v_cvt_pk_bf16_f32 pack, defer-max (THR=8).
// ---------------------------------------------------------------------------
__global__ __launch_bounds__(256, 2)
void attn_mfma(const short* __restrict__ Qhp, const short* __restrict__ Qlp,
               const short* __restrict__ Khg, const short* __restrict__ Klg,
               const short* __restrict__ VtG, const float* __restrict__ Bias2,
               const float* __restrict__ gate, short* __restrict__ Oh,
               short* __restrict__ Ol)
{
    const int bid = blockIdx.x;
    const int h  = bid & 15;
    const int qt = (bid >> 4) & 15;
    const int b  = bid >> 8;

    __shared__ __align__(16) short Kbuf[2][2][64*64];   // [pp][hi/lo][key][d] swz
    __shared__ __align__(16) short Vbuf[2][64*64];      // [pp][d][key-group swz]

    const int t    = threadIdx.x;
    const int w    = t >> 6;
    const int lane = t & 63;
    const int col  = lane & 15;
    const int quad = lane >> 4;

    const size_t headoff = ((size_t)(b*16 + h)) * 2048 * 64;
    const int qb = qt*128 + w*32;

    // ---- Q B-fragments (hi/lo) straight from planes (q pre-scaled) ----
    s8v qfh[2][2], qfl[2][2];
#pragma unroll
    for (int n = 0; n < 2; n++)
#pragma unroll
    for (int c = 0; c < 2; c++) {
        const size_t off = headoff + (size_t)(qb + n*16 + col)*64 + c*32 + quad*8;
        qfh[n][c] = *(const s8v*)(Qhp + off);
        qfl[n][c] = *(const s8v*)(Qlp + off);
    }

    const float g = fminf(fmaxf(gate[h], 0.f), 1.f);

    float mi[2] = {-INFINITY, -INFINITY};
    float li[2] = {0.f, 0.f};
    f4v Oa[4][2];
#pragma unroll
    for (int dt = 0; dt < 4; dt++)
#pragma unroll
        for (int n = 0; n < 2; n++) { f4v z = {0.f,0.f,0.f,0.f}; Oa[dt][n] = z; }

    // ---- staging bases ----
    const short* ksrc_h = Khg + headoff + (size_t)(w*8 + (lane>>3))*64
                          + ((lane&7) ^ (lane>>3))*8;
    const short* ksrc_l = Klg + headoff + (size_t)(w*8 + (lane>>3))*64
                          + ((lane&7) ^ (lane>>3))*8;
    // V^T rows: d = cc*32 + w*8 + (lane>>3); key-group XOR-swizzled by d&7
    const short* vsrcT = VtG + headoff + (size_t)(w*8 + (lane>>3))*2048
                          + ((lane&7) ^ (lane>>3))*8;

    const float* bptr[2];
#pragma unroll
    for (int n = 0; n < 2; n++)
        bptr[n] = Bias2 + (((size_t)b*512 + quad)*2048 + qb + n*16 + col)*4;

    // V read offsets: key = s*16+quad*4+r lives at group (s*2+(quad>>1))^(d&7)
    int vkoff[4];
#pragma unroll
    for (int s = 0; s < 4; s++)
        vkoff[s] = ((((s << 1) | (quad >> 1)) ^ (col & 7)) << 3) + ((quad & 1) << 2);

    auto dma = [&](int kbase, int pp) {
#pragma unroll
        for (int j = 0; j < 2; j++) {
            gl_lds16(ksrc_h + (size_t)kbase*64 + j*2048, &Kbuf[pp][0][(j*4 + w)*512]);
            gl_lds16(ksrc_l + (size_t)kbase*64 + j*2048, &Kbuf[pp][1][(j*4 + w)*512]);
        }
#pragma unroll
        for (int cc = 0; cc < 2; cc++)
            gl_lds16(vsrcT + (size_t)(kbase + cc*65536), &Vbuf[pp][cc*2048 + w*512]);
    };

    float4 biasA[4][2], biasB[4][2];

    // ---- prologue: tile 0 ----
    dma(0, 0);
#pragma unroll
    for (int s = 0; s < 4; s++)
#pragma unroll
    for (int n = 0; n < 2; n++)
        biasA[s][n] = *(const float4*)(bptr[n] + (size_t)s*4*8192);
    __syncthreads();

    auto tile = [&](int kt, int pp, float4 (&BC)[4][2], float4 (&BN)[4][2]) {
        const int kbase = kt * 64;
        const bool pre = kt < 31;
        if (pre) {
            dma(kbase + 64, pp ^ 1);
#pragma unroll
            for (int s = 0; s < 4; s++)
#pragma unroll
            for (int n = 0; n < 2; n++)
                BN[s][n] = *(const float4*)(bptr[n] +
                    ((size_t)((kbase >> 2) + 16) + s*4)*8192);
        }

        // ---- S^T = K·Q^T (3-term hi/lo), scales pre-folded ----
        f4v S[4][2];
#pragma unroll
        for (int s = 0; s < 4; s++)
#pragma unroll
            for (int n = 0; n < 2; n++) { f4v z = {0.f,0.f,0.f,0.f}; S[s][n] = z; }
#pragma unroll
        for (int s = 0; s < 4; s++)
#pragma unroll
        for (int c = 0; c < 2; c++) {
            const int koff = (s*16 + col)*64 + (((c*4 + quad) ^ (col & 7)) << 3);
            s8v kh = *(const s8v*)&Kbuf[pp][0][koff];
            s8v kl = *(const s8v*)&Kbuf[pp][1][koff];
#pragma unroll
            for (int n = 0; n < 2; n++) {
                S[s][n] = mfma32(kh, qfh[n][c], S[s][n]);
                S[s][n] = mfma32(kh, qfl[n][c], S[s][n]);
                S[s][n] = mfma32(kl, qfh[n][c], S[s][n]);
            }
        }

        // ---- bias (1 FMA) + online softmax, defer-max, cvt_pk pack ----
        s4v ph[2][4];
#pragma unroll
        for (int n = 0; n < 2; n++) {
            float sr[4][4];
            float rmax = -INFINITY;
#pragma unroll
            for (int s = 0; s < 4; s++) {
                const float bb[4] = {BC[s][n].x, BC[s][n].y, BC[s][n].z, BC[s][n].w};
#pragma unroll
                for (int r = 0; r < 4; r++) {
                    sr[s][r] = fmaf(bb[r], g, S[s][n][r]);
                    rmax = fmaxf(rmax, sr[s][r]);
                }
            }
            rmax = fmaxf(rmax, __shfl_xor(rmax, 16));
            rmax = fmaxf(rmax, __shfl_xor(rmax, 32));
            if (!__all(rmax <= mi[n] + 8.f)) {          // defer-max THR=8
                const float mnew = fmaxf(mi[n], rmax);
                const float alpha = exp2g(mi[n] - mnew);
#pragma unroll
                for (int dt = 0; dt < 4; dt++)
#pragma unroll
                    for (int r = 0; r < 4; r++) Oa[dt][n][r] *= alpha;
                li[n] *= alpha;
                mi[n] = mnew;
            }
            float rsum = 0.f;
#pragma unroll
            for (int s = 0; s < 4; s++) {
                const float p0 = exp2g(sr[s][0] - mi[n]);
                const float p1 = exp2g(sr[s][1] - mi[n]);
                const float p2 = exp2g(sr[s][2] - mi[n]);
                const float p3 = exp2g(sr[s][3] - mi[n]);
                unsigned u01, u23;
                asm("v_cvt_pk_bf16_f32 %0, %1, %2" : "=v"(u01) : "v"(p0), "v"(p1));
                asm("v_cvt_pk_bf16_f32 %0, %1, %2" : "=v"(u23) : "v"(p2), "v"(p3));
                // exact li from the SAME bf16 weights used in PV
                union { unsigned u; float f; } a0, a1, a2, a3;
                a0.u = u01 << 16; a1.u = u01 & 0xffff0000u;
                a2.u = u23 << 16; a3.u = u23 & 0xffff0000u;
                rsum += (a0.f + a1.f) + (a2.f + a3.f);
                union { unsigned uu[2]; s4v v; } pk;
                pk.uu[0] = u01; pk.uu[1] = u23;
                ph[n][s] = pk.v;
            }
            rsum += __shfl_xor(rsum, 16);
            rsum += __shfl_xor(rsum, 32);
            li[n] += rsum;
        }

        // ---- O^T += V^T·P^T (V^T from swizzled DMA tile) ----
#pragma unroll
        for (int dt = 0; dt < 4; dt++) {
            const int vrow = (dt*16 + col)*64;
#pragma unroll
            for (int s = 0; s < 4; s++) {
                s4v vh = *(const s4v*)&Vbuf[pp][vrow + vkoff[s]];
#pragma unroll
                for (int n = 0; n < 2; n++)
                    Oa[dt][n] = mfma16x16(vh, ph[n][s], Oa[dt][n]);
            }
        }

        if (pre) __syncthreads();   // drains own DMA; all waves done with pp
    };

    for (int kt = 0; kt < 32; kt += 2) {
        tile(kt,     0, biasA, biasB);
        tile(kt + 1, 1, biasB, biasA);
    }

    // ---- epilogue: O^T -> bf16 hi/lo o-planes (B,N,D) ----
#pragma unroll
    for (int n = 0; n < 2; n++) {
        const float inv = 1.0f / li[n];
        const size_t row = (size_t)b*2048 + qb + n*16 + col;
#pragma unroll
        for (int dt = 0; dt < 4; dt++) {
            s4v hv, lv;
#pragma unroll
            for (int r = 0; r < 4; r++) {
                float y = Oa[dt][n][r] * inv;
                unsigned short hb = f2bf(y);
                hv[r] = (short)hb;
                union { float f; unsigned u; } rr; rr.f = y - bf2f(hb);
                lv[r] = (short)(rr.u >> 16);
            }
            const size_t o = row*1024 + h*64 + dt*16 + quad*4;
            *(s4v*)&Oh[o] = hv;
            *(s4v*)&Ol[o] = lv;
        }
    }
}

// ---------------------------------------------------------------------------
extern "C" void kernel_launch(void* const* d_in, const int* in_sizes, int n_in,
                              void* d_out, int out_size, void* d_ws, size_t ws_size,
                              hipStream_t stream)
{
    const float* x    = (const float*)d_in[0];
    const float* cm   = (const float*)d_in[1];
    const float* im   = (const float*)d_in[2];
    const float* Wqkv = (const float*)d_in[3];
    const float* Wout = (const float*)d_in[4];
    const float* qw   = (const float*)d_in[5];
    const float* kw   = (const float*)d_in[6];
    const float* gate = (const float*)d_in[7];
    float* out = (float*)d_out;

    // ---- workspace layout (bytes) ----
    char* ws = (char*)d_ws;
    short* qhp = (short*)(ws);                    // 8.39 MB each
    short* qlp = (short*)(ws +  8388608);
    short* khp = (short*)(ws + 16777216);
    short* klp = (short*)(ws + 25165824);
    short* vp  = (short*)(ws + 33554432);         // V^T[b,h,d,n] bf16
    short* oh  = (short*)(ws + 41943040);
    short* ol  = (short*)(ws + 50331648);
    short* woh = (short*)(ws + 58720256);         // 2.10 MB each
    short* wol = (short*)(ws + 60817408);
    float* rsb = (float*)(ws + 62914560);         // 16 KB
    char*  U   = ws + 62930944;                   // union region
    short* xh  = (short*)(U);                     // 8.39 MB (dead after gemm0)
    short* xl  = (short*)(U +  8388608);
    short* wqh = (short*)(U + 16777216);          // 6.29 MB
    short* wql = (short*)(U + 23068672);
    float* bias2 = (float*)(U);                   // 33.55 MB (after gemm0)

    // 1) split inputs into bf16 hi/lo planes
    planes_k<<<4096, 256, 0, stream>>>(x,    xh,  xl);
    planes_k<<<3072, 256, 0, stream>>>(Wqkv, wqh, wql);
    planes_k<<<1024, 256, 0, stream>>>(Wout, woh, wol);
    // 2) qkv projection (MFMA) + fused rmsnorm -> q/k hi/lo planes, v^T bf16
    gemm_mfma<0,128><<<dim3(24, 32), 256, 0, stream>>>(xh, xl, wqh, wql,
        qhp, qlp, khp, klp, vp, nullptr, qw, kw);
    // 3) bias precompute (overwrites x/wq plane region — dead after gemm0)
    rowscale_k<<<64, 256, 0, stream>>>(cm, rsb);
    bias_pre<<<256, 256, 0, stream>>>(cm, im, rsb, bias2);
    // 4) flash attention -> bf16 o-planes  (512 blocks = 2/CU, q-tile 128)
    attn_mfma<<<512, 256, 0, stream>>>(qhp, qlp, khp, klp, vp, bias2, gate,
                                       oh, ol);
    // 5) output projection (MFMA, 64-row tiles -> 512 blocks) -> fp32 out
    gemm_mfma<1,64><<<dim3(8, 64), 256, 0, stream>>>(oh, ol, woh, wol,
        nullptr, nullptr, nullptr, nullptr, nullptr, out, nullptr, nullptr);
}

// Round 2
// 361.622 us; speedup vs baseline: 1.0899x; 1.0184x over previous
//
#include <hip/hip_runtime.h>
#include <math.h>

// Problem constants: B=2, N=2048, D=1024, H=16, HD=64, C=4

typedef __attribute__((ext_vector_type(8))) short s8v;
typedef __attribute__((ext_vector_type(4))) short s4v;
typedef __attribute__((ext_vector_type(4))) float f4v;

#define L2E 1.44269504088896340736f

__device__ __forceinline__ unsigned short f2bf(float x) {
    union { float f; unsigned u; } v; v.f = x;
    unsigned r = v.u + 0x7FFF + ((v.u >> 16) & 1);
    return (unsigned short)(r >> 16);
}
__device__ __forceinline__ float bf2f(unsigned short h) {
    union { unsigned u; float f; } v; v.u = ((unsigned)h) << 16;
    return v.f;
}
__device__ __forceinline__ f4v mfma32(s8v a, s8v b, f4v c) {
    return __builtin_amdgcn_mfma_f32_16x16x32_bf16(a, b, c, 0, 0, 0);
}
__device__ __forceinline__ void gl_lds16(const void* g, void* l) {
    __builtin_amdgcn_global_load_lds(
        (const __attribute__((address_space(1))) unsigned*)g,
        (__attribute__((address_space(3))) unsigned*)l, 16, 0, 0);
}
// raw v_exp_f32: 1 instr, no OCML range-fixup wrapper
__device__ __forceinline__ float exp2g(float x) {
    float r; asm("v_exp_f32 %0, %1" : "=v"(r) : "v"(x)); return r;
}

// ---------------------------------------------------------------------------
// Split fp32 tensor into bf16 hi/lo planes.
// ---------------------------------------------------------------------------
__global__ __launch_bounds__(256)
void planes_k(const float* __restrict__ src, short* __restrict__ ph,
              short* __restrict__ pl)
{
    const int i = blockIdx.x * 256 + threadIdx.x;
    float4 f = ((const float4*)src)[i];
    float fa[4] = {f.x, f.y, f.z, f.w};
    s4v h4, l4;
#pragma unroll
    for (int j = 0; j < 4; j++) {
        unsigned short hb = f2bf(fa[j]);
        h4[j] = (short)hb;
        l4[j] = (short)f2bf(fa[j] - bf2f(hb));
    }
    ((s4v*)ph)[i] = h4;
    ((s4v*)pl)[i] = l4;
}

// ---------------------------------------------------------------------------
// MFMA GEMM  C[M,NC] = A[M,1024] * B[NC,1024]^T from bf16 hi/lo planes.
// 3-term split.  Tile TM x 128, BK=32.
// MODE 0 (TM=128): fused RMSNorm (q/k; q pre-scaled by 0.125*log2(e)) +
//                  scatter -> q/k hi/lo planes, v written TRANSPOSED
//                  (V^T[b,h,d,n'], bf16) with sigma key permutation
//                  (n' = n with bits [5:4]<->[3:2] swapped) so attn's PV
//                  can read 16x16x32 A-fragments straight from LDS.
// MODE 1 (TM=64):  plain fp32 row-major Cout.
// ---------------------------------------------------------------------------
template<int MODE, int TM>
__global__ __launch_bounds__(256, 3)
void gemm_mfma(const short* __restrict__ Ah, const short* __restrict__ Al,
               const short* __restrict__ Bh, const short* __restrict__ Bl,
               short* __restrict__ Qhp, short* __restrict__ Qlp,
               short* __restrict__ Khp, short* __restrict__ Klp,
               short* __restrict__ Vp, float* __restrict__ Cout,
               const float* __restrict__ qw, const float* __restrict__ kw)
{
    constexpr int MJ = (TM == 128) ? 4 : 2;
    constexpr int JW = (TM == 128) ? 64 : 32;
    __shared__ short sAh[TM*32], sAl[TM*32], sBh[128*32], sBl[128*32];

    const int t = threadIdx.x, w = t >> 6, lane = t & 63;
    const int col = lane & 15, quad = lane >> 4;
    const int wm = (TM == 128) ? (w >> 1) : 0;
    const int wn = (TM == 128) ? (w & 1) : w;
    const int m0 = blockIdx.y * TM, n0 = blockIdx.x * 128;

    f4v acc[4][MJ];
#pragma unroll
    for (int i = 0; i < 4; i++)
#pragma unroll
        for (int j = 0; j < MJ; j++) { f4v z = {0.f,0.f,0.f,0.f}; acc[i][j] = z; }

    const int r4 = lane >> 2;
    const int cs = ((lane & 3) ^ (r4 & 3)) * 8;
    const short* agh = Ah + (size_t)(m0 + w*16 + r4)*1024 + cs;
    const short* agl = Al + (size_t)(m0 + w*16 + r4)*1024 + cs;
    const short* bgh = Bh + (size_t)(n0 + w*16 + r4)*1024 + cs;
    const short* bgl = Bl + (size_t)(n0 + w*16 + r4)*1024 + cs;

    for (int kt = 0; kt < 32; kt++) {
        const int k0 = kt * 32;
        __syncthreads();
#pragma unroll
        for (int j = 0; j < TM/64; j++) {
            gl_lds16(agh + k0 + j*65536, &sAh[(j*4 + w)*512]);
            gl_lds16(agl + k0 + j*65536, &sAl[(j*4 + w)*512]);
        }
#pragma unroll
        for (int j = 0; j < 2; j++) {
            gl_lds16(bgh + k0 + j*65536, &sBh[(j*4 + w)*512]);
            gl_lds16(bgl + k0 + j*65536, &sBl[(j*4 + w)*512]);
        }
        __syncthreads();

        const int swz = ((quad ^ (col & 3)) << 3);
        s8v ahf[4], alf[4], bhf[MJ], blf[MJ];
#pragma unroll
        for (int i = 0; i < 4; i++) {
            const int aoff = (wm*64 + i*16 + col)*32 + swz;
            ahf[i] = *(const s8v*)&sAh[aoff];
            alf[i] = *(const s8v*)&sAl[aoff];
        }
#pragma unroll
        for (int j = 0; j < MJ; j++) {
            const int boff = (wn*JW + j*16 + col)*32 + swz;
            bhf[j] = *(const s8v*)&sBh[boff];
            blf[j] = *(const s8v*)&sBl[boff];
        }
#pragma unroll
        for (int i = 0; i < 4; i++)
#pragma unroll
        for (int j = 0; j < MJ; j++) {
            acc[i][j] = mfma32(ahf[i], bhf[j], acc[i][j]);
            acc[i][j] = mfma32(ahf[i], blf[j], acc[i][j]);
            acc[i][j] = mfma32(alf[i], bhf[j], acc[i][j]);
        }
    }

    if (MODE == 0) {
        // fused RMSNorm over HD=64; q additionally folded with 0.125*log2(e)
        const int whichW = (n0 + wn*64) >> 10;      // wave-uniform: 0=q,1=k,2=v
        if (whichW < 2) {
            const float* nw = (whichW == 0) ? qw : kw;
            const float sfac = (whichW == 0) ? (0.125f * L2E) : 1.0f;
            float wj[4];
#pragma unroll
            for (int j = 0; j < 4; j++) wj[j] = nw[j*16 + col] * sfac;
#pragma unroll
            for (int i = 0; i < 4; i++)
#pragma unroll
            for (int r = 0; r < 4; r++) {
                float s2 = acc[i][0][r]*acc[i][0][r] + acc[i][1][r]*acc[i][1][r]
                         + acc[i][2][r]*acc[i][2][r] + acc[i][3][r]*acc[i][3][r];
                s2 += __shfl_xor(s2, 1);
                s2 += __shfl_xor(s2, 2);
                s2 += __shfl_xor(s2, 4);
                s2 += __shfl_xor(s2, 8);
                const float scn = rsqrtf(s2*(1.0f/64.0f) + 1e-6f);
#pragma unroll
                for (int j = 0; j < 4; j++) acc[i][j][r] *= scn*wj[j];
            }
        }
    }

    if (MODE == 0) {
#pragma unroll
        for (int i = 0; i < 4; i++)
#pragma unroll
        for (int j = 0; j < MJ; j++) {
            const int gcol = n0 + wn*JW + j*16 + col;
            const int which = gcol >> 10;           // wave-uniform
            const int hh = (gcol >> 6) & 15;
            const int hd = gcol & 63;
            const int grow0 = m0 + wm*64 + i*16 + quad*4;
            const int b = grow0 >> 11, nn0 = grow0 & 2047;
            if (which == 2) {
                // V^T[b,h,d,n'] bf16, sigma key permutation within 64-block
                s4v hv;
#pragma unroll
                for (int r = 0; r < 4; r++) hv[r] = (short)f2bf(acc[i][j][r]);
                const int nswz = (nn0 & ~60) | ((nn0 & 12) << 2) | ((nn0 & 48) >> 2);
                *(s4v*)&Vp[((size_t)(b*16 + hh)*64 + hd)*2048 + nswz] = hv;
            } else {
                short* Hp = (which == 0) ? Qhp : Khp;
                short* Lp = (which == 0) ? Qlp : Klp;
                const size_t base = ((size_t)(b*16 + hh)*2048 + nn0)*64 + hd;
#pragma unroll
                for (int r = 0; r < 4; r++) {
                    const float v = acc[i][j][r];
                    const unsigned short hb = f2bf(v);
                    union { float f; unsigned u; } rr; rr.f = v - bf2f(hb);
                    Hp[base + (size_t)r*64] = (short)hb;
                    Lp[base + (size_t)r*64] = (short)(rr.u >> 16);
                }
            }
        }
    } else {
#pragma unroll
        for (int i = 0; i < 4; i++)
#pragma unroll
        for (int j = 0; j < MJ; j++) {
            const int gcol = n0 + wn*JW + j*16 + col;
#pragma unroll
            for (int r = 0; r < 4; r++) {
                const int grow = m0 + wm*64 + i*16 + quad*4 + r;
                Cout[(size_t)grow*1024 + gcol] = acc[i][j][r];
            }
        }
    }
}

// ---------------------------------------------------------------------------
// rowscale[b,q] = 1 / max(max_k dot4(cm[b,:,q], cm[b,:,k]), 1e-6)
// ---------------------------------------------------------------------------
__global__ __launch_bounds__(256)
void rowscale_k(const float* __restrict__ cm, float* __restrict__ rs)
{
    __shared__ float cms[4][2048];
    const int b  = blockIdx.x >> 5;
    const int qt = blockIdx.x & 31;
    const float* base = cm + (size_t)b * 4 * 2048;
    for (int i = threadIdx.x; i < 2048; i += 256) {
        cms[0][i] = base[i];
        cms[1][i] = base[2048 + i];
        cms[2][i] = base[4096 + i];
        cms[3][i] = base[6144 + i];
    }
    __syncthreads();
    const int q    = qt * 64 + (threadIdx.x >> 2);
    const int part = threadIdx.x & 3;
    const float a0 = cms[0][q], a1 = cms[1][q], a2 = cms[2][q], a3 = cms[3][q];
    float mx = 0.f;
    for (int i = 0; i < 512; i++) {
        const int k = part + 4 * i;
        float d = a0*cms[0][k] + a1*cms[1][k] + a2*cms[2][k] + a3*cms[3][k];
        mx = fmaxf(mx, d);
    }
    mx = fmaxf(mx, __shfl_xor(mx, 1));
    mx = fmaxf(mx, __shfl_xor(mx, 2));
    if (part == 0) rs[b * 2048 + q] = 1.0f / fmaxf(mx, 1e-6f);
}

// ---------------------------------------------------------------------------
// Bias precompute, pre-scaled by 3*log2(e) (gate applied in attn):
//  Bias2[b][k>>2][q][k&3] = ((dot4*rsq - 0.5)*2 + 0.3*im) * 3*L2E
// ---------------------------------------------------------------------------
__global__ __launch_bounds__(256)
void bias_pre(const float* __restrict__ cm, const float* __restrict__ im,
              const float* __restrict__ rs, float* __restrict__ Bias2)
{
    const int bid = blockIdx.x;
    const int qq = bid & 3;
    const int kt = (bid >> 2) & 31;
    const int b  = bid >> 7;

    __shared__ float cmk[4][64];
    const int t = threadIdx.x;
    const int k0 = kt * 64;
    cmk[t >> 6][t & 63] = cm[(size_t)b*8192 + (t >> 6)*2048 + k0 + (t & 63)];
    __syncthreads();

    const int klane = t & 15;
    const int qrow  = t >> 4;
    const int kk = k0 + klane*4;
    const int kg = kk >> 2;
    float ck[4][4];
#pragma unroll
    for (int c = 0; c < 4; c++)
#pragma unroll
        for (int j = 0; j < 4; j++) ck[c][j] = cmk[c][klane*4 + j];

    const float* cmb = cm + (size_t)b * 8192;
    const float kS = 3.0f * L2E;
    for (int it = 0; it < 32; it++) {
        const int q = qq*512 + it*16 + qrow;
        float4 imv = *(const float4*)(im + ((size_t)b*2048 + q)*2048 + kk);
        const float rsq = rs[b*2048 + q];
        const float c0 = cmb[q], c1 = cmb[2048+q], c2 = cmb[4096+q], c3 = cmb[6144+q];
        float o[4];
        float iv[4] = {imv.x, imv.y, imv.z, imv.w};
#pragma unroll
        for (int j = 0; j < 4; j++) {
            float same = c0*ck[0][j] + c1*ck[1][j] + c2*ck[2][j] + c3*ck[3][j];
            o[j] = ((same*rsq - 0.5f)*2.0f + 0.3f*iv[j]) * kS;
        }
        *(float4*)(Bias2 + (((size_t)b*512 + kg)*2048 + q)*4) =
            make_float4(o[0], o[1], o[2], o[3]);
    }
}

// ---------------------------------------------------------------------------
// Flash attention, S^T orientation.  q-tile 128 (32 q/wave), 512 blocks,
// 2 blocks/CU.  K AND V staged by global_load_lds DMA (double-buffered,
// XOR source swizzle); V arrives sigma-permuted+pre-transposed so PV runs
// as 16x16x32 MFMA with conflict-free b128 LDS reads and zero shuffles.
// li accumulated by MFMA (ones-vector row-sum).  One barrier per tile.
// Softmax: folded scales, tree-max, raw v_exp_f32, cvt_pk pack,
// defer-max (THR=8, log2 domain).
// ---------------------------------------------------------------------------
__global__ __launch_bounds__(256, 2)
void attn_mfma(const short* __restrict__ Qhp, const short* __restrict__ Qlp,
               const short* __restrict__ Khg, const short* __restrict__ Klg,
               const short* __restrict__ VtG, const float* __restrict__ Bias2,
               const float* __restrict__ gate, short* __restrict__ Oh,
               short* __restrict__ Ol)
{
    const int bid = blockIdx.x;
    const int h  = bid & 15;
    const int qt = (bid >> 4) & 15;
    const int b  = bid >> 8;

    __shared__ __align__(16) short Kbuf[2][2][64*64];   // [pp][hi/lo][key][d] swz
    __shared__ __align__(16) short Vbuf[2][64*64];      // [pp][d][sigma-key swz]

    const int t    = threadIdx.x;
    const int w    = t >> 6;
    const int lane = t & 63;
    const int col  = lane & 15;
    const int quad = lane >> 4;

    const size_t headoff = ((size_t)(b*16 + h)) * 2048 * 64;
    const int qb = qt*128 + w*32;

    // ---- Q B-fragments (hi/lo) straight from planes (q pre-scaled) ----
    s8v qfh[2][2], qfl[2][2];
#pragma unroll
    for (int n = 0; n < 2; n++)
#pragma unroll
    for (int c = 0; c < 2; c++) {
        const size_t off = headoff + (size_t)(qb + n*16 + col)*64 + c*32 + quad*8;
        qfh[n][c] = *(const s8v*)(Qhp + off);
        qfl[n][c] = *(const s8v*)(Qlp + off);
    }

    const float g = fminf(fmaxf(gate[h], 0.f), 1.f);

    s8v ones8;
#pragma unroll
    for (int j = 0; j < 8; j++) ones8[j] = (short)0x3F80;   // bf16 1.0

    float mi[2] = {-INFINITY, -INFINITY};
    f4v liacc[2];
    f4v Oa[4][2];
    {
        f4v z = {0.f,0.f,0.f,0.f};
        liacc[0] = z; liacc[1] = z;
#pragma unroll
        for (int dt = 0; dt < 4; dt++)
#pragma unroll
            for (int n = 0; n < 2; n++) Oa[dt][n] = z;
    }

    // ---- staging bases ----
    const short* ksrc_h = Khg + headoff + (size_t)(w*8 + (lane>>3))*64
                          + ((lane&7) ^ (lane>>3))*8;
    const short* ksrc_l = Klg + headoff + (size_t)(w*8 + (lane>>3))*64
                          + ((lane&7) ^ (lane>>3))*8;
    // V^T rows: d = cc*32 + w*8 + (lane>>3); sigma-key-group XOR by d&7
    const short* vsrcT = VtG + headoff + (size_t)(w*8 + (lane>>3))*2048
                          + ((lane&7) ^ (lane>>3))*8;

    const float* bptr[2];
#pragma unroll
    for (int n = 0; n < 2; n++)
        bptr[n] = Bias2 + (((size_t)b*512 + quad)*2048 + qb + n*16 + col)*4;

    auto dma = [&](int kbase, int pp) {
#pragma unroll
        for (int j = 0; j < 2; j++) {
            gl_lds16(ksrc_h + (size_t)kbase*64 + j*2048, &Kbuf[pp][0][(j*4 + w)*512]);
            gl_lds16(ksrc_l + (size_t)kbase*64 + j*2048, &Kbuf[pp][1][(j*4 + w)*512]);
        }
#pragma unroll
        for (int cc = 0; cc < 2; cc++)
            gl_lds16(vsrcT + (size_t)(kbase + cc*65536), &Vbuf[pp][cc*2048 + w*512]);
    };

    float4 biasA[4][2], biasB[4][2];

    // ---- prologue: tile 0 ----
    dma(0, 0);
#pragma unroll
    for (int s = 0; s < 4; s++)
#pragma unroll
    for (int n = 0; n < 2; n++)
        biasA[s][n] = *(const float4*)(bptr[n] + (size_t)s*4*8192);
    __syncthreads();

    auto tile = [&](int kt, int pp, float4 (&BC)[4][2], float4 (&BN)[4][2]) {
        const int kbase = kt * 64;
        const bool pre = kt < 31;
        if (pre) {
            dma(kbase + 64, pp ^ 1);
#pragma unroll
            for (int s = 0; s < 4; s++)
#pragma unroll
            for (int n = 0; n < 2; n++)
                BN[s][n] = *(const float4*)(bptr[n] +
                    ((size_t)((kbase >> 2) + 16) + s*4)*8192);
        }

        // ---- S^T = K·Q^T (3-term hi/lo), scales pre-folded ----
        f4v S[4][2];
#pragma unroll
        for (int s = 0; s < 4; s++)
#pragma unroll
            for (int n = 0; n < 2; n++) { f4v z = {0.f,0.f,0.f,0.f}; S[s][n] = z; }
#pragma unroll
        for (int s = 0; s < 4; s++)
#pragma unroll
        for (int c = 0; c < 2; c++) {
            const int koff = (s*16 + col)*64 + (((c*4 + quad) ^ (col & 7)) << 3);
            s8v kh = *(const s8v*)&Kbuf[pp][0][koff];
            s8v kl = *(const s8v*)&Kbuf[pp][1][koff];
#pragma unroll
            for (int n = 0; n < 2; n++) {
                S[s][n] = mfma32(kh, qfh[n][c], S[s][n]);
                S[s][n] = mfma32(kh, qfl[n][c], S[s][n]);
                S[s][n] = mfma32(kl, qfh[n][c], S[s][n]);
            }
        }

        // ---- bias (1 FMA) + online softmax, defer-max, cvt_pk pack ----
        s8v ph8[2][2];
#pragma unroll
        for (int n = 0; n < 2; n++) {
            float sr[4][4];
#pragma unroll
            for (int s = 0; s < 4; s++) {
                const float bb[4] = {BC[s][n].x, BC[s][n].y, BC[s][n].z, BC[s][n].w};
#pragma unroll
                for (int r = 0; r < 4; r++)
                    sr[s][r] = fmaf(bb[r], g, S[s][n][r]);
            }
            // tree max (depth 4)
            float mx[4];
#pragma unroll
            for (int s = 0; s < 4; s++)
                mx[s] = fmaxf(fmaxf(sr[s][0], sr[s][1]),
                              fmaxf(sr[s][2], sr[s][3]));
            float rmax = fmaxf(fmaxf(mx[0], mx[1]), fmaxf(mx[2], mx[3]));
            rmax = fmaxf(rmax, __shfl_xor(rmax, 16));
            rmax = fmaxf(rmax, __shfl_xor(rmax, 32));
            if (!__all(rmax <= mi[n] + 8.f)) {          // defer-max THR=8
                const float mnew = fmaxf(mi[n], rmax);
                const float alpha = exp2g(mi[n] - mnew);
#pragma unroll
                for (int dt = 0; dt < 4; dt++)
#pragma unroll
                    for (int r = 0; r < 4; r++) Oa[dt][n][r] *= alpha;
                liacc[n][0] *= alpha;
                mi[n] = mnew;
            }
            union { unsigned uu[4]; s8v v; } pk0, pk1;
#pragma unroll
            for (int s = 0; s < 4; s++) {
                const float p0 = exp2g(sr[s][0] - mi[n]);
                const float p1 = exp2g(sr[s][1] - mi[n]);
                const float p2 = exp2g(sr[s][2] - mi[n]);
                const float p3 = exp2g(sr[s][3] - mi[n]);
                unsigned u01, u23;
                asm("v_cvt_pk_bf16_f32 %0, %1, %2" : "=v"(u01) : "v"(p0), "v"(p1));
                asm("v_cvt_pk_bf16_f32 %0, %1, %2" : "=v"(u23) : "v"(p2), "v"(p3));
                if (s < 2) { pk0.uu[s*2] = u01;     pk0.uu[s*2 + 1] = u23; }
                else       { pk1.uu[(s-2)*2] = u01; pk1.uu[(s-2)*2 + 1] = u23; }
            }
            ph8[n][0] = pk0.v;
            ph8[n][1] = pk1.v;
        }

        // ---- li row-sum by MFMA (rows of C identical; only [0] consumed) ----
#pragma unroll
        for (int n = 0; n < 2; n++)
#pragma unroll
        for (int m = 0; m < 2; m++)
            liacc[n] = mfma32(ones8, ph8[n][m], liacc[n]);

        // ---- O^T += V^T·P^T  (16x16x32, conflict-free b128 V reads) ----
#pragma unroll
        for (int dt = 0; dt < 4; dt++) {
            const int vrow = (dt*16 + col)*64;
            s8v v0 = *(const s8v*)&Vbuf[pp][vrow + ((((quad*2)    ) ^ (col & 7)) << 3)];
            s8v v1 = *(const s8v*)&Vbuf[pp][vrow + ((((quad*2) + 1) ^ (col & 7)) << 3)];
#pragma unroll
            for (int n = 0; n < 2; n++) {
                Oa[dt][n] = mfma32(v0, ph8[n][0], Oa[dt][n]);
                Oa[dt][n] = mfma32(v1, ph8[n][1], Oa[dt][n]);
            }
        }

        if (pre) __syncthreads();   // drains own DMA; all waves done with pp
    };

    for (int kt = 0; kt < 32; kt += 2) {
        tile(kt,     0, biasA, biasB);
        tile(kt + 1, 1, biasB, biasA);
    }

    // ---- epilogue: O^T -> bf16 hi/lo o-planes (B,N,D) ----
#pragma unroll
    for (int n = 0; n < 2; n++) {
        const float inv = 1.0f / liacc[n][0];
        const size_t row = (size_t)b*2048 + qb + n*16 + col;
#pragma unroll
        for (int dt = 0; dt < 4; dt++) {
            s4v hv, lv;
#pragma unroll
            for (int r = 0; r < 4; r++) {
                float y = Oa[dt][n][r] * inv;
                unsigned short hb = f2bf(y);
                hv[r] = (short)hb;
                union { float f; unsigned u; } rr; rr.f = y - bf2f(hb);
                lv[r] = (short)(rr.u >> 16);
            }
            const size_t o = row*1024 + h*64 + dt*16 + quad*4;
            *(s4v*)&Oh[o] = hv;
            *(s4v*)&Ol[o] = lv;
        }
    }
}

// ---------------------------------------------------------------------------
extern "C" void kernel_launch(void* const* d_in, const int* in_sizes, int n_in,
                              void* d_out, int out_size, void* d_ws, size_t ws_size,
                              hipStream_t stream)
{
    const float* x    = (const float*)d_in[0];
    const float* cm   = (const float*)d_in[1];
    const float* im   = (const float*)d_in[2];
    const float* Wqkv = (const float*)d_in[3];
    const float* Wout = (const float*)d_in[4];
    const float* qw   = (const float*)d_in[5];
    const float* kw   = (const float*)d_in[6];
    const float* gate = (const float*)d_in[7];
    float* out = (float*)d_out;

    // ---- workspace layout (bytes) ----
    char* ws = (char*)d_ws;
    short* qhp = (short*)(ws);                    // 8.39 MB each
    short* qlp = (short*)(ws +  8388608);
    short* khp = (short*)(ws + 16777216);
    short* klp = (short*)(ws + 25165824);
    short* vp  = (short*)(ws + 33554432);         // V^T[b,h,d,n'] bf16 (sigma)
    short* oh  = (short*)(ws + 41943040);
    short* ol  = (short*)(ws + 50331648);
    short* woh = (short*)(ws + 58720256);         // 2.10 MB each
    short* wol = (short*)(ws + 60817408);
    float* rsb = (float*)(ws + 62914560);         // 16 KB
    char*  U   = ws + 62930944;                   // union region
    short* xh  = (short*)(U);                     // 8.39 MB (dead after gemm0)
    short* xl  = (short*)(U +  8388608);
    short* wqh = (short*)(U + 16777216);          // 6.29 MB
    short* wql = (short*)(U + 23068672);
    float* bias2 = (float*)(U);                   // 33.55 MB (after gemm0)

    // 1) split inputs into bf16 hi/lo planes
    planes_k<<<4096, 256, 0, stream>>>(x,    xh,  xl);
    planes_k<<<3072, 256, 0, stream>>>(Wqkv, wqh, wql);
    planes_k<<<1024, 256, 0, stream>>>(Wout, woh, wol);
    // 2) qkv projection (MFMA) + fused rmsnorm -> q/k hi/lo planes, v^T bf16
    gemm_mfma<0,128><<<dim3(24, 32), 256, 0, stream>>>(xh, xl, wqh, wql,
        qhp, qlp, khp, klp, vp, nullptr, qw, kw);
    // 3) bias precompute (overwrites x/wq plane region — dead after gemm0)
    rowscale_k<<<64, 256, 0, stream>>>(cm, rsb);
    bias_pre<<<256, 256, 0, stream>>>(cm, im, rsb, bias2);
    // 4) flash attention -> bf16 o-planes  (512 blocks = 2/CU, q-tile 128)
    attn_mfma<<<512, 256, 0, stream>>>(qhp, qlp, khp, klp, vp, bias2, gate,
                                       oh, ol);
    // 5) output projection (MFMA, 64-row tiles -> 512 blocks) -> fp32 out
    gemm_mfma<1,64><<<dim3(8, 64), 256, 0, stream>>>(oh, ol, woh, wol,
        nullptr, nullptr, nullptr, nullptr, nullptr, out, nullptr, nullptr);
}

// Round 3
// 354.563 us; speedup vs baseline: 1.1116x; 1.0199x over previous
//
#include <hip/hip_runtime.h>
#include <math.h>

// Problem constants: B=2, N=2048, D=1024, H=16, HD=64, C=4

typedef __attribute__((ext_vector_type(8))) short s8v;
typedef __attribute__((ext_vector_type(4))) short s4v;
typedef __attribute__((ext_vector_type(4))) float f4v;

#define L2E 1.44269504088896340736f

__device__ __forceinline__ unsigned short f2bf(float x) {
    union { float f; unsigned u; } v; v.f = x;
    unsigned r = v.u + 0x7FFF + ((v.u >> 16) & 1);
    return (unsigned short)(r >> 16);
}
__device__ __forceinline__ float bf2f(unsigned short h) {
    union { unsigned u; float f; } v; v.u = ((unsigned)h) << 16;
    return v.f;
}
__device__ __forceinline__ f4v mfma32(s8v a, s8v b, f4v c) {
    return __builtin_amdgcn_mfma_f32_16x16x32_bf16(a, b, c, 0, 0, 0);
}
__device__ __forceinline__ void gl_lds16(const void* g, void* l) {
    __builtin_amdgcn_global_load_lds(
        (const __attribute__((address_space(1))) unsigned*)g,
        (__attribute__((address_space(3))) unsigned*)l, 16, 0, 0);
}
// raw v_exp_f32: 1 instr, no OCML range-fixup wrapper
__device__ __forceinline__ float exp2g(float x) {
    float r; asm("v_exp_f32 %0, %1" : "=v"(r) : "v"(x)); return r;
}

// ---------------------------------------------------------------------------
// Split fp32 tensor into bf16 hi/lo planes.
// ---------------------------------------------------------------------------
__global__ __launch_bounds__(256)
void planes_k(const float* __restrict__ src, short* __restrict__ ph,
              short* __restrict__ pl)
{
    const int i = blockIdx.x * 256 + threadIdx.x;
    float4 f = ((const float4*)src)[i];
    float fa[4] = {f.x, f.y, f.z, f.w};
    s4v h4, l4;
#pragma unroll
    for (int j = 0; j < 4; j++) {
        unsigned short hb = f2bf(fa[j]);
        h4[j] = (short)hb;
        l4[j] = (short)f2bf(fa[j] - bf2f(hb));
    }
    ((s4v*)ph)[i] = h4;
    ((s4v*)pl)[i] = l4;
}

// ---------------------------------------------------------------------------
// MFMA GEMM  C[M,NC] = A[M,1024] * B[NC,1024]^T from bf16 hi/lo planes.
// 3-term split.  Tile TM x 128, BK=32.
// MODE 0 (TM=128): fused RMSNorm (q/k; q pre-scaled by 0.125*log2(e)) +
//                  scatter -> q/k hi/lo planes, v written TRANSPOSED
//                  (V^T[b,h,d,n'], bf16) with sigma key permutation
//                  (n' = n with bits [5:4]<->[3:2] swapped) so attn's PV
//                  can read 16x16x32 A-fragments straight from LDS.
// MODE 1 (TM=64):  plain fp32 row-major Cout.
// ---------------------------------------------------------------------------
template<int MODE, int TM>
__global__ __launch_bounds__(256, 3)
void gemm_mfma(const short* __restrict__ Ah, const short* __restrict__ Al,
               const short* __restrict__ Bh, const short* __restrict__ Bl,
               short* __restrict__ Qhp, short* __restrict__ Qlp,
               short* __restrict__ Khp, short* __restrict__ Klp,
               short* __restrict__ Vp, float* __restrict__ Cout,
               const float* __restrict__ qw, const float* __restrict__ kw)
{
    constexpr int MJ = (TM == 128) ? 4 : 2;
    constexpr int JW = (TM == 128) ? 64 : 32;
    __shared__ short sAh[TM*32], sAl[TM*32], sBh[128*32], sBl[128*32];

    const int t = threadIdx.x, w = t >> 6, lane = t & 63;
    const int col = lane & 15, quad = lane >> 4;
    const int wm = (TM == 128) ? (w >> 1) : 0;
    const int wn = (TM == 128) ? (w & 1) : w;
    const int m0 = blockIdx.y * TM, n0 = blockIdx.x * 128;

    f4v acc[4][MJ];
#pragma unroll
    for (int i = 0; i < 4; i++)
#pragma unroll
        for (int j = 0; j < MJ; j++) { f4v z = {0.f,0.f,0.f,0.f}; acc[i][j] = z; }

    const int r4 = lane >> 2;
    const int cs = ((lane & 3) ^ (r4 & 3)) * 8;
    const short* agh = Ah + (size_t)(m0 + w*16 + r4)*1024 + cs;
    const short* agl = Al + (size_t)(m0 + w*16 + r4)*1024 + cs;
    const short* bgh = Bh + (size_t)(n0 + w*16 + r4)*1024 + cs;
    const short* bgl = Bl + (size_t)(n0 + w*16 + r4)*1024 + cs;

    for (int kt = 0; kt < 32; kt++) {
        const int k0 = kt * 32;
        __syncthreads();
#pragma unroll
        for (int j = 0; j < TM/64; j++) {
            gl_lds16(agh + k0 + j*65536, &sAh[(j*4 + w)*512]);
            gl_lds16(agl + k0 + j*65536, &sAl[(j*4 + w)*512]);
        }
#pragma unroll
        for (int j = 0; j < 2; j++) {
            gl_lds16(bgh + k0 + j*65536, &sBh[(j*4 + w)*512]);
            gl_lds16(bgl + k0 + j*65536, &sBl[(j*4 + w)*512]);
        }
        __syncthreads();

        const int swz = ((quad ^ (col & 3)) << 3);
        s8v ahf[4], alf[4], bhf[MJ], blf[MJ];
#pragma unroll
        for (int i = 0; i < 4; i++) {
            const int aoff = (wm*64 + i*16 + col)*32 + swz;
            ahf[i] = *(const s8v*)&sAh[aoff];
            alf[i] = *(const s8v*)&sAl[aoff];
        }
#pragma unroll
        for (int j = 0; j < MJ; j++) {
            const int boff = (wn*JW + j*16 + col)*32 + swz;
            bhf[j] = *(const s8v*)&sBh[boff];
            blf[j] = *(const s8v*)&sBl[boff];
        }
#pragma unroll
        for (int i = 0; i < 4; i++)
#pragma unroll
        for (int j = 0; j < MJ; j++) {
            acc[i][j] = mfma32(ahf[i], bhf[j], acc[i][j]);
            acc[i][j] = mfma32(ahf[i], blf[j], acc[i][j]);
            acc[i][j] = mfma32(alf[i], bhf[j], acc[i][j]);
        }
    }

    if (MODE == 0) {
        // fused RMSNorm over HD=64; q additionally folded with 0.125*log2(e)
        const int whichW = (n0 + wn*64) >> 10;      // wave-uniform: 0=q,1=k,2=v
        if (whichW < 2) {
            const float* nw = (whichW == 0) ? qw : kw;
            const float sfac = (whichW == 0) ? (0.125f * L2E) : 1.0f;
            float wj[4];
#pragma unroll
            for (int j = 0; j < 4; j++) wj[j] = nw[j*16 + col] * sfac;
#pragma unroll
            for (int i = 0; i < 4; i++)
#pragma unroll
            for (int r = 0; r < 4; r++) {
                float s2 = acc[i][0][r]*acc[i][0][r] + acc[i][1][r]*acc[i][1][r]
                         + acc[i][2][r]*acc[i][2][r] + acc[i][3][r]*acc[i][3][r];
                s2 += __shfl_xor(s2, 1);
                s2 += __shfl_xor(s2, 2);
                s2 += __shfl_xor(s2, 4);
                s2 += __shfl_xor(s2, 8);
                const float scn = rsqrtf(s2*(1.0f/64.0f) + 1e-6f);
#pragma unroll
                for (int j = 0; j < 4; j++) acc[i][j][r] *= scn*wj[j];
            }
        }
    }

    if (MODE == 0) {
#pragma unroll
        for (int i = 0; i < 4; i++)
#pragma unroll
        for (int j = 0; j < MJ; j++) {
            const int gcol = n0 + wn*JW + j*16 + col;
            const int which = gcol >> 10;           // wave-uniform
            const int hh = (gcol >> 6) & 15;
            const int hd = gcol & 63;
            const int grow0 = m0 + wm*64 + i*16 + quad*4;
            const int b = grow0 >> 11, nn0 = grow0 & 2047;
            if (which == 2) {
                // V^T[b,h,d,n'] bf16, sigma key permutation within 64-block
                s4v hv;
#pragma unroll
                for (int r = 0; r < 4; r++) hv[r] = (short)f2bf(acc[i][j][r]);
                const int nswz = (nn0 & ~60) | ((nn0 & 12) << 2) | ((nn0 & 48) >> 2);
                *(s4v*)&Vp[((size_t)(b*16 + hh)*64 + hd)*2048 + nswz] = hv;
            } else {
                short* Hp = (which == 0) ? Qhp : Khp;
                short* Lp = (which == 0) ? Qlp : Klp;
                const size_t base = ((size_t)(b*16 + hh)*2048 + nn0)*64 + hd;
#pragma unroll
                for (int r = 0; r < 4; r++) {
                    const float v = acc[i][j][r];
                    const unsigned short hb = f2bf(v);
                    union { float f; unsigned u; } rr; rr.f = v - bf2f(hb);
                    Hp[base + (size_t)r*64] = (short)hb;
                    Lp[base + (size_t)r*64] = (short)(rr.u >> 16);
                }
            }
        }
    } else {
#pragma unroll
        for (int i = 0; i < 4; i++)
#pragma unroll
        for (int j = 0; j < MJ; j++) {
            const int gcol = n0 + wn*JW + j*16 + col;
#pragma unroll
            for (int r = 0; r < 4; r++) {
                const int grow = m0 + wm*64 + i*16 + quad*4 + r;
                Cout[(size_t)grow*1024 + gcol] = acc[i][j][r];
            }
        }
    }
}

// ---------------------------------------------------------------------------
// rowscale[b,q] = 1 / max(max_k dot4(cm[b,:,q], cm[b,:,k]), 1e-6)
// ---------------------------------------------------------------------------
__global__ __launch_bounds__(256)
void rowscale_k(const float* __restrict__ cm, float* __restrict__ rs)
{
    __shared__ float cms[4][2048];
    const int b  = blockIdx.x >> 5;
    const int qt = blockIdx.x & 31;
    const float* base = cm + (size_t)b * 4 * 2048;
    for (int i = threadIdx.x; i < 2048; i += 256) {
        cms[0][i] = base[i];
        cms[1][i] = base[2048 + i];
        cms[2][i] = base[4096 + i];
        cms[3][i] = base[6144 + i];
    }
    __syncthreads();
    const int q    = qt * 64 + (threadIdx.x >> 2);
    const int part = threadIdx.x & 3;
    const float a0 = cms[0][q], a1 = cms[1][q], a2 = cms[2][q], a3 = cms[3][q];
    float mx = 0.f;
    for (int i = 0; i < 512; i++) {
        const int k = part + 4 * i;
        float d = a0*cms[0][k] + a1*cms[1][k] + a2*cms[2][k] + a3*cms[3][k];
        mx = fmaxf(mx, d);
    }
    mx = fmaxf(mx, __shfl_xor(mx, 1));
    mx = fmaxf(mx, __shfl_xor(mx, 2));
    if (part == 0) rs[b * 2048 + q] = 1.0f / fmaxf(mx, 1e-6f);
}

// ---------------------------------------------------------------------------
// Bias precompute, pre-scaled by 3*log2(e) (gate applied in attn):
//  Bias2[b][k>>2][q][k&3] = ((dot4*rsq - 0.5)*2 + 0.3*im) * 3*L2E
// ---------------------------------------------------------------------------
__global__ __launch_bounds__(256)
void bias_pre(const float* __restrict__ cm, const float* __restrict__ im,
              const float* __restrict__ rs, float* __restrict__ Bias2)
{
    const int bid = blockIdx.x;
    const int qq = bid & 3;
    const int kt = (bid >> 2) & 31;
    const int b  = bid >> 7;

    __shared__ float cmk[4][64];
    const int t = threadIdx.x;
    const int k0 = kt * 64;
    cmk[t >> 6][t & 63] = cm[(size_t)b*8192 + (t >> 6)*2048 + k0 + (t & 63)];
    __syncthreads();

    const int klane = t & 15;
    const int qrow  = t >> 4;
    const int kk = k0 + klane*4;
    const int kg = kk >> 2;
    float ck[4][4];
#pragma unroll
    for (int c = 0; c < 4; c++)
#pragma unroll
        for (int j = 0; j < 4; j++) ck[c][j] = cmk[c][klane*4 + j];

    const float* cmb = cm + (size_t)b * 8192;
    const float kS = 3.0f * L2E;
    for (int it = 0; it < 32; it++) {
        const int q = qq*512 + it*16 + qrow;
        float4 imv = *(const float4*)(im + ((size_t)b*2048 + q)*2048 + kk);
        const float rsq = rs[b*2048 + q];
        const float c0 = cmb[q], c1 = cmb[2048+q], c2 = cmb[4096+q], c3 = cmb[6144+q];
        float o[4];
        float iv[4] = {imv.x, imv.y, imv.z, imv.w};
#pragma unroll
        for (int j = 0; j < 4; j++) {
            float same = c0*ck[0][j] + c1*ck[1][j] + c2*ck[2][j] + c3*ck[3][j];
            o[j] = ((same*rsq - 0.5f)*2.0f + 0.3f*iv[j]) * kS;
        }
        *(float4*)(Bias2 + (((size_t)b*512 + kg)*2048 + q)*4) =
            make_float4(o[0], o[1], o[2], o[3]);
    }
}

// ---------------------------------------------------------------------------
// Flash attention, S^T orientation.  q-tile 128 (32 q/wave), 512 blocks,
// 2 blocks/CU.  K AND V staged by global_load_lds DMA (double-buffered,
// XOR source swizzle); V arrives sigma-permuted+pre-transposed so PV runs
// as 16x16x32 MFMA with conflict-free b128 LDS reads and zero shuffles.
// li accumulated by MFMA (ones-vector row-sum).  One barrier per tile.
// Softmax: NO-MAX (scores provably bounded |sr|<=17.2 by RMSNorm
// Cauchy-Schwarz + bias bound; exp2 range-safe in bf16) -> zero cross-lane
// ops, zero DS shuffles, pure per-lane fma->exp2->cvt_pk stream.
// ---------------------------------------------------------------------------
__global__ __launch_bounds__(256, 2)
void attn_mfma(const short* __restrict__ Qhp, const short* __restrict__ Qlp,
               const short* __restrict__ Khg, const short* __restrict__ Klg,
               const short* __restrict__ VtG, const float* __restrict__ Bias2,
               const float* __restrict__ gate, short* __restrict__ Oh,
               short* __restrict__ Ol)
{
    const int bid = blockIdx.x;
    const int h  = bid & 15;
    const int qt = (bid >> 4) & 15;
    const int b  = bid >> 8;

    __shared__ __align__(16) short Kbuf[2][2][64*64];   // [pp][hi/lo][key][d] swz
    __shared__ __align__(16) short Vbuf[2][64*64];      // [pp][d][sigma-key swz]

    const int t    = threadIdx.x;
    const int w    = t >> 6;
    const int lane = t & 63;
    const int col  = lane & 15;
    const int quad = lane >> 4;

    const size_t headoff = ((size_t)(b*16 + h)) * 2048 * 64;
    const int qb = qt*128 + w*32;

    // ---- Q B-fragments (hi/lo) straight from planes (q pre-scaled) ----
    s8v qfh[2][2], qfl[2][2];
#pragma unroll
    for (int n = 0; n < 2; n++)
#pragma unroll
    for (int c = 0; c < 2; c++) {
        const size_t off = headoff + (size_t)(qb + n*16 + col)*64 + c*32 + quad*8;
        qfh[n][c] = *(const s8v*)(Qhp + off);
        qfl[n][c] = *(const s8v*)(Qlp + off);
    }

    const float g = fminf(fmaxf(gate[h], 0.f), 1.f);

    s8v ones8;
#pragma unroll
    for (int j = 0; j < 8; j++) ones8[j] = (short)0x3F80;   // bf16 1.0

    f4v liacc[2];
    f4v Oa[4][2];
    {
        f4v z = {0.f,0.f,0.f,0.f};
        liacc[0] = z; liacc[1] = z;
#pragma unroll
        for (int dt = 0; dt < 4; dt++)
#pragma unroll
            for (int n = 0; n < 2; n++) Oa[dt][n] = z;
    }

    // ---- staging bases ----
    const short* ksrc_h = Khg + headoff + (size_t)(w*8 + (lane>>3))*64
                          + ((lane&7) ^ (lane>>3))*8;
    const short* ksrc_l = Klg + headoff + (size_t)(w*8 + (lane>>3))*64
                          + ((lane&7) ^ (lane>>3))*8;
    // V^T rows: d = cc*32 + w*8 + (lane>>3); sigma-key-group XOR by d&7
    const short* vsrcT = VtG + headoff + (size_t)(w*8 + (lane>>3))*2048
                          + ((lane&7) ^ (lane>>3))*8;

    const float* bptr[2];
#pragma unroll
    for (int n = 0; n < 2; n++)
        bptr[n] = Bias2 + (((size_t)b*512 + quad)*2048 + qb + n*16 + col)*4;

    auto dma = [&](int kbase, int pp) {
#pragma unroll
        for (int j = 0; j < 2; j++) {
            gl_lds16(ksrc_h + (size_t)kbase*64 + j*2048, &Kbuf[pp][0][(j*4 + w)*512]);
            gl_lds16(ksrc_l + (size_t)kbase*64 + j*2048, &Kbuf[pp][1][(j*4 + w)*512]);
        }
#pragma unroll
        for (int cc = 0; cc < 2; cc++)
            gl_lds16(vsrcT + (size_t)(kbase + cc*65536), &Vbuf[pp][cc*2048 + w*512]);
    };

    float4 biasA[4][2], biasB[4][2];

    // ---- prologue: tile 0 ----
    dma(0, 0);
#pragma unroll
    for (int s = 0; s < 4; s++)
#pragma unroll
    for (int n = 0; n < 2; n++)
        biasA[s][n] = *(const float4*)(bptr[n] + (size_t)s*4*8192);
    __syncthreads();

    auto tile = [&](int kt, int pp, float4 (&BC)[4][2], float4 (&BN)[4][2]) {
        const int kbase = kt * 64;
        const bool pre = kt < 31;
        if (pre) {
            dma(kbase + 64, pp ^ 1);
#pragma unroll
            for (int s = 0; s < 4; s++)
#pragma unroll
            for (int n = 0; n < 2; n++)
                BN[s][n] = *(const float4*)(bptr[n] +
                    ((size_t)((kbase >> 2) + 16) + s*4)*8192);
        }

        // ---- S^T = K·Q^T (3-term hi/lo), scales pre-folded ----
        f4v S[4][2];
#pragma unroll
        for (int s = 0; s < 4; s++)
#pragma unroll
            for (int n = 0; n < 2; n++) { f4v z = {0.f,0.f,0.f,0.f}; S[s][n] = z; }
#pragma unroll
        for (int s = 0; s < 4; s++)
#pragma unroll
        for (int c = 0; c < 2; c++) {
            const int koff = (s*16 + col)*64 + (((c*4 + quad) ^ (col & 7)) << 3);
            s8v kh = *(const s8v*)&Kbuf[pp][0][koff];
            s8v kl = *(const s8v*)&Kbuf[pp][1][koff];
#pragma unroll
            for (int n = 0; n < 2; n++) {
                S[s][n] = mfma32(kh, qfh[n][c], S[s][n]);
                S[s][n] = mfma32(kh, qfl[n][c], S[s][n]);
                S[s][n] = mfma32(kl, qfh[n][c], S[s][n]);
            }
        }

        // ---- bias (1 FMA) + no-max softmax: p = exp2(S + g*bias) ----
        s8v ph8[2][2];
#pragma unroll
        for (int n = 0; n < 2; n++) {
            union { unsigned uu[4]; s8v v; } pk0, pk1;
#pragma unroll
            for (int s = 0; s < 4; s++) {
                const float bb[4] = {BC[s][n].x, BC[s][n].y, BC[s][n].z, BC[s][n].w};
                const float p0 = exp2g(fmaf(bb[0], g, S[s][n][0]));
                const float p1 = exp2g(fmaf(bb[1], g, S[s][n][1]));
                const float p2 = exp2g(fmaf(bb[2], g, S[s][n][2]));
                const float p3 = exp2g(fmaf(bb[3], g, S[s][n][3]));
                unsigned u01, u23;
                asm("v_cvt_pk_bf16_f32 %0, %1, %2" : "=v"(u01) : "v"(p0), "v"(p1));
                asm("v_cvt_pk_bf16_f32 %0, %1, %2" : "=v"(u23) : "v"(p2), "v"(p3));
                if (s < 2) { pk0.uu[s*2] = u01;     pk0.uu[s*2 + 1] = u23; }
                else       { pk1.uu[(s-2)*2] = u01; pk1.uu[(s-2)*2 + 1] = u23; }
            }
            ph8[n][0] = pk0.v;
            ph8[n][1] = pk1.v;
        }

        // ---- li row-sum by MFMA (rows of C identical; only [0] consumed) ----
#pragma unroll
        for (int n = 0; n < 2; n++)
#pragma unroll
        for (int m = 0; m < 2; m++)
            liacc[n] = mfma32(ones8, ph8[n][m], liacc[n]);

        // ---- O^T += V^T·P^T  (16x16x32, conflict-free b128 V reads) ----
#pragma unroll
        for (int dt = 0; dt < 4; dt++) {
            const int vrow = (dt*16 + col)*64;
            s8v v0 = *(const s8v*)&Vbuf[pp][vrow + ((((quad*2)    ) ^ (col & 7)) << 3)];
            s8v v1 = *(const s8v*)&Vbuf[pp][vrow + ((((quad*2) + 1) ^ (col & 7)) << 3)];
#pragma unroll
            for (int n = 0; n < 2; n++) {
                Oa[dt][n] = mfma32(v0, ph8[n][0], Oa[dt][n]);
                Oa[dt][n] = mfma32(v1, ph8[n][1], Oa[dt][n]);
            }
        }

        if (pre) __syncthreads();   // drains own DMA; all waves done with pp
    };

    for (int kt = 0; kt < 32; kt += 2) {
        tile(kt,     0, biasA, biasB);
        tile(kt + 1, 1, biasB, biasA);
    }

    // ---- epilogue: O^T -> bf16 hi/lo o-planes (B,N,D) ----
#pragma unroll
    for (int n = 0; n < 2; n++) {
        const float inv = 1.0f / liacc[n][0];
        const size_t row = (size_t)b*2048 + qb + n*16 + col;
#pragma unroll
        for (int dt = 0; dt < 4; dt++) {
            s4v hv, lv;
#pragma unroll
            for (int r = 0; r < 4; r++) {
                float y = Oa[dt][n][r] * inv;
                unsigned short hb = f2bf(y);
                hv[r] = (short)hb;
                union { float f; unsigned u; } rr; rr.f = y - bf2f(hb);
                lv[r] = (short)(rr.u >> 16);
            }
            const size_t o = row*1024 + h*64 + dt*16 + quad*4;
            *(s4v*)&Oh[o] = hv;
            *(s4v*)&Ol[o] = lv;
        }
    }
}

// ---------------------------------------------------------------------------
extern "C" void kernel_launch(void* const* d_in, const int* in_sizes, int n_in,
                              void* d_out, int out_size, void* d_ws, size_t ws_size,
                              hipStream_t stream)
{
    const float* x    = (const float*)d_in[0];
    const float* cm   = (const float*)d_in[1];
    const float* im   = (const float*)d_in[2];
    const float* Wqkv = (const float*)d_in[3];
    const float* Wout = (const float*)d_in[4];
    const float* qw   = (const float*)d_in[5];
    const float* kw   = (const float*)d_in[6];
    const float* gate = (const float*)d_in[7];
    float* out = (float*)d_out;

    // ---- workspace layout (bytes) ----
    char* ws = (char*)d_ws;
    short* qhp = (short*)(ws);                    // 8.39 MB each
    short* qlp = (short*)(ws +  8388608);
    short* khp = (short*)(ws + 16777216);
    short* klp = (short*)(ws + 25165824);
    short* vp  = (short*)(ws + 33554432);         // V^T[b,h,d,n'] bf16 (sigma)
    short* oh  = (short*)(ws + 41943040);
    short* ol  = (short*)(ws + 50331648);
    short* woh = (short*)(ws + 58720256);         // 2.10 MB each
    short* wol = (short*)(ws + 60817408);
    float* rsb = (float*)(ws + 62914560);         // 16 KB
    char*  U   = ws + 62930944;                   // union region
    short* xh  = (short*)(U);                     // 8.39 MB (dead after gemm0)
    short* xl  = (short*)(U +  8388608);
    short* wqh = (short*)(U + 16777216);          // 6.29 MB
    short* wql = (short*)(U + 23068672);
    float* bias2 = (float*)(U);                   // 33.55 MB (after gemm0)

    // 1) split inputs into bf16 hi/lo planes
    planes_k<<<4096, 256, 0, stream>>>(x,    xh,  xl);
    planes_k<<<3072, 256, 0, stream>>>(Wqkv, wqh, wql);
    planes_k<<<1024, 256, 0, stream>>>(Wout, woh, wol);
    // 2) qkv projection (MFMA) + fused rmsnorm -> q/k hi/lo planes, v^T bf16
    gemm_mfma<0,128><<<dim3(24, 32), 256, 0, stream>>>(xh, xl, wqh, wql,
        qhp, qlp, khp, klp, vp, nullptr, qw, kw);
    // 3) bias precompute (overwrites x/wq plane region — dead after gemm0)
    rowscale_k<<<64, 256, 0, stream>>>(cm, rsb);
    bias_pre<<<256, 256, 0, stream>>>(cm, im, rsb, bias2);
    // 4) flash attention -> bf16 o-planes  (512 blocks = 2/CU, q-tile 128)
    attn_mfma<<<512, 256, 0, stream>>>(qhp, qlp, khp, klp, vp, bias2, gate,
                                       oh, ol);
    // 5) output projection (MFMA, 64-row tiles -> 512 blocks) -> fp32 out
    gemm_mfma<1,64><<<dim3(8, 64), 256, 0, stream>>>(oh, ol, woh, wol,
        nullptr, nullptr, nullptr, nullptr, nullptr, out, nullptr, nullptr);
}

// Round 4
// 351.491 us; speedup vs baseline: 1.1214x; 1.0087x over previous
//
#include <hip/hip_runtime.h>
#include <math.h>

// Problem constants: B=2, N=2048, D=1024, H=16, HD=64, C=4

typedef __attribute__((ext_vector_type(8))) short s8v;
typedef __attribute__((ext_vector_type(4))) short s4v;
typedef __attribute__((ext_vector_type(4))) float f4v;

#define L2E 1.44269504088896340736f

__device__ __forceinline__ unsigned short f2bf(float x) {
    union { float f; unsigned u; } v; v.f = x;
    unsigned r = v.u + 0x7FFF + ((v.u >> 16) & 1);
    return (unsigned short)(r >> 16);
}
__device__ __forceinline__ float bf2f(unsigned short h) {
    union { unsigned u; float f; } v; v.u = ((unsigned)h) << 16;
    return v.f;
}
__device__ __forceinline__ f4v mfma32(s8v a, s8v b, f4v c) {
    return __builtin_amdgcn_mfma_f32_16x16x32_bf16(a, b, c, 0, 0, 0);
}
__device__ __forceinline__ void gl_lds16(const void* g, void* l) {
    __builtin_amdgcn_global_load_lds(
        (const __attribute__((address_space(1))) unsigned*)g,
        (__attribute__((address_space(3))) unsigned*)l, 16, 0, 0);
}
// raw v_exp_f32: 1 instr, no OCML range-fixup wrapper
__device__ __forceinline__ float exp2g(float x) {
    float r; asm("v_exp_f32 %0, %1" : "=v"(r) : "v"(x)); return r;
}

// ---------------------------------------------------------------------------
// Split fp32 tensor into bf16 hi/lo planes.
// ---------------------------------------------------------------------------
__global__ __launch_bounds__(256)
void planes_k(const float* __restrict__ src, short* __restrict__ ph,
              short* __restrict__ pl)
{
    const int i = blockIdx.x * 256 + threadIdx.x;
    float4 f = ((const float4*)src)[i];
    float fa[4] = {f.x, f.y, f.z, f.w};
    s4v h4, l4;
#pragma unroll
    for (int j = 0; j < 4; j++) {
        unsigned short hb = f2bf(fa[j]);
        h4[j] = (short)hb;
        l4[j] = (short)f2bf(fa[j] - bf2f(hb));
    }
    ((s4v*)ph)[i] = h4;
    ((s4v*)pl)[i] = l4;
}

// ---------------------------------------------------------------------------
// QKV projection GEMM, 256x256 tile, BK=32, 8 waves, DOUBLE-BUFFERED LDS
// (128 KB dynamic).  3-term bf16 hi/lo split.  Per K-step: prefetch k+1
// issued BEFORE compute of k; single barrier drains it after ~96 MFMA of
// cover.  Fused RMSNorm (q pre-scaled by 0.125*log2(e)); scatter to q/k
// hi/lo planes and sigma-permuted V^T.
// ---------------------------------------------------------------------------
__global__ __launch_bounds__(512, 2)
void gemm_qkv(const short* __restrict__ Ah, const short* __restrict__ Al,
              const short* __restrict__ Bh, const short* __restrict__ Bl,
              short* __restrict__ Qhp, short* __restrict__ Qlp,
              short* __restrict__ Khp, short* __restrict__ Klp,
              short* __restrict__ Vp,
              const float* __restrict__ qw, const float* __restrict__ kw)
{
    extern __shared__ short L[];           // 65536 shorts = 128 KB
    short* sAh = L;                        // [2][8192]
    short* sAl = L + 16384;
    short* sBh = L + 32768;
    short* sBl = L + 49152;

    const int t = threadIdx.x, w = t >> 6, lane = t & 63;
    const int col = lane & 15, quad = lane >> 4;
    const int wm = w >> 2;                 // 0..1 -> 128-row half
    const int wn = w & 3;                  // 0..3 -> 64-col quarter
    const int m0 = blockIdx.y * 256, n0 = blockIdx.x * 256;

    f4v acc[8][4];
#pragma unroll
    for (int i = 0; i < 8; i++)
#pragma unroll
        for (int j = 0; j < 4; j++) { f4v z = {0.f,0.f,0.f,0.f}; acc[i][j] = z; }

    // staging: wave w, sub j stages rows (j*8+w)*16 + r4; chunk XOR swizzle.
    const int r4 = lane >> 2;
    const int cs = ((lane & 3) ^ (r4 & 3)) * 8;
    const short* agh = Ah + (size_t)(m0 + w*16 + r4)*1024 + cs;
    const short* agl = Al + (size_t)(m0 + w*16 + r4)*1024 + cs;
    const short* bgh = Bh + (size_t)(n0 + w*16 + r4)*1024 + cs;
    const short* bgl = Bl + (size_t)(n0 + w*16 + r4)*1024 + cs;

    auto stage = [&](int k0, int pp) {
        const int dbase = pp*8192 + w*512;
#pragma unroll
        for (int j = 0; j < 2; j++) {
            gl_lds16(agh + k0 + j*131072, &sAh[dbase + j*4096]);
            gl_lds16(agl + k0 + j*131072, &sAl[dbase + j*4096]);
            gl_lds16(bgh + k0 + j*131072, &sBh[dbase + j*4096]);
            gl_lds16(bgl + k0 + j*131072, &sBl[dbase + j*4096]);
        }
    };

    stage(0, 0);
    __syncthreads();

    for (int kt = 0; kt < 32; kt++) {
        const int pp = kt & 1;
        if (kt < 31) stage((kt + 1) * 32, pp ^ 1);

        const int swz = ((quad ^ (col & 3)) << 3);
        s8v bhf[4], blf[4];
#pragma unroll
        for (int j = 0; j < 4; j++) {
            const int boff = pp*8192 + (wn*64 + j*16 + col)*32 + swz;
            bhf[j] = *(const s8v*)&sBh[boff];
            blf[j] = *(const s8v*)&sBl[boff];
        }
#pragma unroll
        for (int i = 0; i < 8; i++) {
            const int aoff = pp*8192 + (wm*128 + i*16 + col)*32 + swz;
            s8v ah = *(const s8v*)&sAh[aoff];
            s8v al = *(const s8v*)&sAl[aoff];
#pragma unroll
            for (int j = 0; j < 4; j++) {
                acc[i][j] = mfma32(ah, bhf[j], acc[i][j]);
                acc[i][j] = mfma32(ah, blf[j], acc[i][j]);
                acc[i][j] = mfma32(al, bhf[j], acc[i][j]);
            }
        }
        __syncthreads();
    }

    // ---- fused RMSNorm over HD=64 (q pre-scaled by 0.125*log2(e)) ----
    const int whichW = (n0 + wn*64) >> 10;      // wave-uniform: 0=q,1=k,2=v
    if (whichW < 2) {
        const float* nw = (whichW == 0) ? qw : kw;
        const float sfac = (whichW == 0) ? (0.125f * L2E) : 1.0f;
        float wj[4];
#pragma unroll
        for (int j = 0; j < 4; j++) wj[j] = nw[j*16 + col] * sfac;
#pragma unroll
        for (int i = 0; i < 8; i++)
#pragma unroll
        for (int r = 0; r < 4; r++) {
            float s2 = acc[i][0][r]*acc[i][0][r] + acc[i][1][r]*acc[i][1][r]
                     + acc[i][2][r]*acc[i][2][r] + acc[i][3][r]*acc[i][3][r];
            s2 += __shfl_xor(s2, 1);
            s2 += __shfl_xor(s2, 2);
            s2 += __shfl_xor(s2, 4);
            s2 += __shfl_xor(s2, 8);
            const float scn = rsqrtf(s2*(1.0f/64.0f) + 1e-6f);
#pragma unroll
            for (int j = 0; j < 4; j++) acc[i][j][r] *= scn*wj[j];
        }
    }

    // ---- scatter ----
#pragma unroll
    for (int i = 0; i < 8; i++)
#pragma unroll
    for (int j = 0; j < 4; j++) {
        const int gcol = n0 + wn*64 + j*16 + col;
        const int which = gcol >> 10;           // wave-uniform
        const int hh = (gcol >> 6) & 15;
        const int hd = gcol & 63;
        const int grow0 = m0 + wm*128 + i*16 + quad*4;
        const int b = grow0 >> 11, nn0 = grow0 & 2047;
        if (which == 2) {
            // V^T[b,h,d,n'] bf16, sigma key permutation within 64-block
            s4v hv;
#pragma unroll
            for (int r = 0; r < 4; r++) hv[r] = (short)f2bf(acc[i][j][r]);
            const int nswz = (nn0 & ~60) | ((nn0 & 12) << 2) | ((nn0 & 48) >> 2);
            *(s4v*)&Vp[((size_t)(b*16 + hh)*64 + hd)*2048 + nswz] = hv;
        } else {
            short* Hp = (which == 0) ? Qhp : Khp;
            short* Lp = (which == 0) ? Qlp : Klp;
            const size_t base = ((size_t)(b*16 + hh)*2048 + nn0)*64 + hd;
#pragma unroll
            for (int r = 0; r < 4; r++) {
                const float v = acc[i][j][r];
                const unsigned short hb = f2bf(v);
                union { float f; unsigned u; } rr; rr.f = v - bf2f(hb);
                Hp[base + (size_t)r*64] = (short)hb;
                Lp[base + (size_t)r*64] = (short)(rr.u >> 16);
            }
        }
    }
}

// ---------------------------------------------------------------------------
// Output-projection GEMM (MODE1 of the old template): C[M,1024] fp32.
// Tile 64x128, BK=32, single-buffered (unchanged this round).
// ---------------------------------------------------------------------------
template<int TM>
__global__ __launch_bounds__(256, 3)
void gemm_out(const short* __restrict__ Ah, const short* __restrict__ Al,
              const short* __restrict__ Bh, const short* __restrict__ Bl,
              float* __restrict__ Cout)
{
    constexpr int MJ = 2;
    constexpr int JW = 32;
    __shared__ short sAh[TM*32], sAl[TM*32], sBh[128*32], sBl[128*32];

    const int t = threadIdx.x, w = t >> 6, lane = t & 63;
    const int col = lane & 15, quad = lane >> 4;
    const int wm = 0;
    const int wn = w;
    const int m0 = blockIdx.y * TM, n0 = blockIdx.x * 128;

    f4v acc[4][MJ];
#pragma unroll
    for (int i = 0; i < 4; i++)
#pragma unroll
        for (int j = 0; j < MJ; j++) { f4v z = {0.f,0.f,0.f,0.f}; acc[i][j] = z; }

    const int r4 = lane >> 2;
    const int cs = ((lane & 3) ^ (r4 & 3)) * 8;
    const short* agh = Ah + (size_t)(m0 + w*16 + r4)*1024 + cs;
    const short* agl = Al + (size_t)(m0 + w*16 + r4)*1024 + cs;
    const short* bgh = Bh + (size_t)(n0 + w*16 + r4)*1024 + cs;
    const short* bgl = Bl + (size_t)(n0 + w*16 + r4)*1024 + cs;

    for (int kt = 0; kt < 32; kt++) {
        const int k0 = kt * 32;
        __syncthreads();
#pragma unroll
        for (int j = 0; j < TM/64; j++) {
            gl_lds16(agh + k0 + j*65536, &sAh[(j*4 + w)*512]);
            gl_lds16(agl + k0 + j*65536, &sAl[(j*4 + w)*512]);
        }
#pragma unroll
        for (int j = 0; j < 2; j++) {
            gl_lds16(bgh + k0 + j*65536, &sBh[(j*4 + w)*512]);
            gl_lds16(bgl + k0 + j*65536, &sBl[(j*4 + w)*512]);
        }
        __syncthreads();

        const int swz = ((quad ^ (col & 3)) << 3);
        s8v ahf[4], alf[4], bhf[MJ], blf[MJ];
#pragma unroll
        for (int i = 0; i < 4; i++) {
            const int aoff = (wm*64 + i*16 + col)*32 + swz;
            ahf[i] = *(const s8v*)&sAh[aoff];
            alf[i] = *(const s8v*)&sAl[aoff];
        }
#pragma unroll
        for (int j = 0; j < MJ; j++) {
            const int boff = (wn*JW + j*16 + col)*32 + swz;
            bhf[j] = *(const s8v*)&sBh[boff];
            blf[j] = *(const s8v*)&sBl[boff];
        }
#pragma unroll
        for (int i = 0; i < 4; i++)
#pragma unroll
        for (int j = 0; j < MJ; j++) {
            acc[i][j] = mfma32(ahf[i], bhf[j], acc[i][j]);
            acc[i][j] = mfma32(ahf[i], blf[j], acc[i][j]);
            acc[i][j] = mfma32(alf[i], bhf[j], acc[i][j]);
        }
    }

#pragma unroll
    for (int i = 0; i < 4; i++)
#pragma unroll
    for (int j = 0; j < MJ; j++) {
        const int gcol = n0 + wn*JW + j*16 + col;
#pragma unroll
        for (int r = 0; r < 4; r++) {
            const int grow = m0 + wm*64 + i*16 + quad*4 + r;
            Cout[(size_t)grow*1024 + gcol] = acc[i][j][r];
        }
    }
}

// ---------------------------------------------------------------------------
// rowscale[b,q] = 1 / max(max_k dot4(cm[b,:,q], cm[b,:,k]), 1e-6)
// ---------------------------------------------------------------------------
__global__ __launch_bounds__(256)
void rowscale_k(const float* __restrict__ cm, float* __restrict__ rs)
{
    __shared__ float cms[4][2048];
    const int b  = blockIdx.x >> 5;
    const int qt = blockIdx.x & 31;
    const float* base = cm + (size_t)b * 4 * 2048;
    for (int i = threadIdx.x; i < 2048; i += 256) {
        cms[0][i] = base[i];
        cms[1][i] = base[2048 + i];
        cms[2][i] = base[4096 + i];
        cms[3][i] = base[6144 + i];
    }
    __syncthreads();
    const int q    = qt * 64 + (threadIdx.x >> 2);
    const int part = threadIdx.x & 3;
    const float a0 = cms[0][q], a1 = cms[1][q], a2 = cms[2][q], a3 = cms[3][q];
    float mx = 0.f;
    for (int i = 0; i < 512; i++) {
        const int k = part + 4 * i;
        float d = a0*cms[0][k] + a1*cms[1][k] + a2*cms[2][k] + a3*cms[3][k];
        mx = fmaxf(mx, d);
    }
    mx = fmaxf(mx, __shfl_xor(mx, 1));
    mx = fmaxf(mx, __shfl_xor(mx, 2));
    if (part == 0) rs[b * 2048 + q] = 1.0f / fmaxf(mx, 1e-6f);
}

// ---------------------------------------------------------------------------
// Bias precompute, pre-scaled by 3*log2(e) (gate applied in attn):
//  Bias2[b][k>>2][q][k&3] = ((dot4*rsq - 0.5)*2 + 0.3*im) * 3*L2E
// ---------------------------------------------------------------------------
__global__ __launch_bounds__(256)
void bias_pre(const float* __restrict__ cm, const float* __restrict__ im,
              const float* __restrict__ rs, float* __restrict__ Bias2)
{
    const int bid = blockIdx.x;
    const int qq = bid & 3;
    const int kt = (bid >> 2) & 31;
    const int b  = bid >> 7;

    __shared__ float cmk[4][64];
    const int t = threadIdx.x;
    const int k0 = kt * 64;
    cmk[t >> 6][t & 63] = cm[(size_t)b*8192 + (t >> 6)*2048 + k0 + (t & 63)];
    __syncthreads();

    const int klane = t & 15;
    const int qrow  = t >> 4;
    const int kk = k0 + klane*4;
    const int kg = kk >> 2;
    float ck[4][4];
#pragma unroll
    for (int c = 0; c < 4; c++)
#pragma unroll
        for (int j = 0; j < 4; j++) ck[c][j] = cmk[c][klane*4 + j];

    const float* cmb = cm + (size_t)b * 8192;
    const float kS = 3.0f * L2E;
    for (int it = 0; it < 32; it++) {
        const int q = qq*512 + it*16 + qrow;
        float4 imv = *(const float4*)(im + ((size_t)b*2048 + q)*2048 + kk);
        const float rsq = rs[b*2048 + q];
        const float c0 = cmb[q], c1 = cmb[2048+q], c2 = cmb[4096+q], c3 = cmb[6144+q];
        float o[4];
        float iv[4] = {imv.x, imv.y, imv.z, imv.w};
#pragma unroll
        for (int j = 0; j < 4; j++) {
            float same = c0*ck[0][j] + c1*ck[1][j] + c2*ck[2][j] + c3*ck[3][j];
            o[j] = ((same*rsq - 0.5f)*2.0f + 0.3f*iv[j]) * kS;
        }
        *(float4*)(Bias2 + (((size_t)b*512 + kg)*2048 + q)*4) =
            make_float4(o[0], o[1], o[2], o[3]);
    }
}

// ---------------------------------------------------------------------------
// Flash attention, S^T orientation.  q-tile 128 (32 q/wave), 512 blocks,
// 2 blocks/CU.  K AND V staged by global_load_lds DMA (double-buffered,
// XOR source swizzle); V arrives sigma-permuted+pre-transposed so PV runs
// as 16x16x32 MFMA with conflict-free b128 LDS reads and zero shuffles.
// li accumulated by MFMA (ones-vector row-sum).  One barrier per tile.
// Softmax: NO-MAX (scores provably bounded |sr|<=17.2 by RMSNorm
// Cauchy-Schwarz + bias bound; exp2 range-safe in bf16) -> zero cross-lane
// ops, zero DS shuffles, pure per-lane fma->exp2->cvt_pk stream.
// ---------------------------------------------------------------------------
__global__ __launch_bounds__(256, 2)
void attn_mfma(const short* __restrict__ Qhp, const short* __restrict__ Qlp,
               const short* __restrict__ Khg, const short* __restrict__ Klg,
               const short* __restrict__ VtG, const float* __restrict__ Bias2,
               const float* __restrict__ gate, short* __restrict__ Oh,
               short* __restrict__ Ol)
{
    const int bid = blockIdx.x;
    const int h  = bid & 15;
    const int qt = (bid >> 4) & 15;
    const int b  = bid >> 8;

    __shared__ __align__(16) short Kbuf[2][2][64*64];   // [pp][hi/lo][key][d] swz
    __shared__ __align__(16) short Vbuf[2][64*64];      // [pp][d][sigma-key swz]

    const int t    = threadIdx.x;
    const int w    = t >> 6;
    const int lane = t & 63;
    const int col  = lane & 15;
    const int quad = lane >> 4;

    const size_t headoff = ((size_t)(b*16 + h)) * 2048 * 64;
    const int qb = qt*128 + w*32;

    // ---- Q B-fragments (hi/lo) straight from planes (q pre-scaled) ----
    s8v qfh[2][2], qfl[2][2];
#pragma unroll
    for (int n = 0; n < 2; n++)
#pragma unroll
    for (int c = 0; c < 2; c++) {
        const size_t off = headoff + (size_t)(qb + n*16 + col)*64 + c*32 + quad*8;
        qfh[n][c] = *(const s8v*)(Qhp + off);
        qfl[n][c] = *(const s8v*)(Qlp + off);
    }

    const float g = fminf(fmaxf(gate[h], 0.f), 1.f);

    s8v ones8;
#pragma unroll
    for (int j = 0; j < 8; j++) ones8[j] = (short)0x3F80;   // bf16 1.0

    f4v liacc[2];
    f4v Oa[4][2];
    {
        f4v z = {0.f,0.f,0.f,0.f};
        liacc[0] = z; liacc[1] = z;
#pragma unroll
        for (int dt = 0; dt < 4; dt++)
#pragma unroll
            for (int n = 0; n < 2; n++) Oa[dt][n] = z;
    }

    // ---- staging bases ----
    const short* ksrc_h = Khg + headoff + (size_t)(w*8 + (lane>>3))*64
                          + ((lane&7) ^ (lane>>3))*8;
    const short* ksrc_l = Klg + headoff + (size_t)(w*8 + (lane>>3))*64
                          + ((lane&7) ^ (lane>>3))*8;
    // V^T rows: d = cc*32 + w*8 + (lane>>3); sigma-key-group XOR by d&7
    const short* vsrcT = VtG + headoff + (size_t)(w*8 + (lane>>3))*2048
                          + ((lane&7) ^ (lane>>3))*8;

    const float* bptr[2];
#pragma unroll
    for (int n = 0; n < 2; n++)
        bptr[n] = Bias2 + (((size_t)b*512 + quad)*2048 + qb + n*16 + col)*4;

    auto dma = [&](int kbase, int pp) {
#pragma unroll
        for (int j = 0; j < 2; j++) {
            gl_lds16(ksrc_h + (size_t)kbase*64 + j*2048, &Kbuf[pp][0][(j*4 + w)*512]);
            gl_lds16(ksrc_l + (size_t)kbase*64 + j*2048, &Kbuf[pp][1][(j*4 + w)*512]);
        }
#pragma unroll
        for (int cc = 0; cc < 2; cc++)
            gl_lds16(vsrcT + (size_t)(kbase + cc*65536), &Vbuf[pp][cc*2048 + w*512]);
    };

    float4 biasA[4][2], biasB[4][2];

    // ---- prologue: tile 0 ----
    dma(0, 0);
#pragma unroll
    for (int s = 0; s < 4; s++)
#pragma unroll
    for (int n = 0; n < 2; n++)
        biasA[s][n] = *(const float4*)(bptr[n] + (size_t)s*4*8192);
    __syncthreads();

    auto tile = [&](int kt, int pp, float4 (&BC)[4][2], float4 (&BN)[4][2]) {
        const int kbase = kt * 64;
        const bool pre = kt < 31;
        if (pre) {
            dma(kbase + 64, pp ^ 1);
#pragma unroll
            for (int s = 0; s < 4; s++)
#pragma unroll
            for (int n = 0; n < 2; n++)
                BN[s][n] = *(const float4*)(bptr[n] +
                    ((size_t)((kbase >> 2) + 16) + s*4)*8192);
        }

        // ---- S^T = K·Q^T (3-term hi/lo), scales pre-folded ----
        f4v S[4][2];
#pragma unroll
        for (int s = 0; s < 4; s++)
#pragma unroll
            for (int n = 0; n < 2; n++) { f4v z = {0.f,0.f,0.f,0.f}; S[s][n] = z; }
#pragma unroll
        for (int s = 0; s < 4; s++)
#pragma unroll
        for (int c = 0; c < 2; c++) {
            const int koff = (s*16 + col)*64 + (((c*4 + quad) ^ (col & 7)) << 3);
            s8v kh = *(const s8v*)&Kbuf[pp][0][koff];
            s8v kl = *(const s8v*)&Kbuf[pp][1][koff];
#pragma unroll
            for (int n = 0; n < 2; n++) {
                S[s][n] = mfma32(kh, qfh[n][c], S[s][n]);
                S[s][n] = mfma32(kh, qfl[n][c], S[s][n]);
                S[s][n] = mfma32(kl, qfh[n][c], S[s][n]);
            }
        }

        // ---- bias (1 FMA) + no-max softmax: p = exp2(S + g*bias) ----
        s8v ph8[2][2];
#pragma unroll
        for (int n = 0; n < 2; n++) {
            union { unsigned uu[4]; s8v v; } pk0, pk1;
#pragma unroll
            for (int s = 0; s < 4; s++) {
                const float bb[4] = {BC[s][n].x, BC[s][n].y, BC[s][n].z, BC[s][n].w};
                const float p0 = exp2g(fmaf(bb[0], g, S[s][n][0]));
                const float p1 = exp2g(fmaf(bb[1], g, S[s][n][1]));
                const float p2 = exp2g(fmaf(bb[2], g, S[s][n][2]));
                const float p3 = exp2g(fmaf(bb[3], g, S[s][n][3]));
                unsigned u01, u23;
                asm("v_cvt_pk_bf16_f32 %0, %1, %2" : "=v"(u01) : "v"(p0), "v"(p1));
                asm("v_cvt_pk_bf16_f32 %0, %1, %2" : "=v"(u23) : "v"(p2), "v"(p3));
                if (s < 2) { pk0.uu[s*2] = u01;     pk0.uu[s*2 + 1] = u23; }
                else       { pk1.uu[(s-2)*2] = u01; pk1.uu[(s-2)*2 + 1] = u23; }
            }
            ph8[n][0] = pk0.v;
            ph8[n][1] = pk1.v;
        }

        // ---- li row-sum by MFMA (rows of C identical; only [0] consumed) ----
#pragma unroll
        for (int n = 0; n < 2; n++)
#pragma unroll
        for (int m = 0; m < 2; m++)
            liacc[n] = mfma32(ones8, ph8[n][m], liacc[n]);

        // ---- O^T += V^T·P^T  (16x16x32, conflict-free b128 V reads) ----
#pragma unroll
        for (int dt = 0; dt < 4; dt++) {
            const int vrow = (dt*16 + col)*64;
            s8v v0 = *(const s8v*)&Vbuf[pp][vrow + ((((quad*2)    ) ^ (col & 7)) << 3)];
            s8v v1 = *(const s8v*)&Vbuf[pp][vrow + ((((quad*2) + 1) ^ (col & 7)) << 3)];
#pragma unroll
            for (int n = 0; n < 2; n++) {
                Oa[dt][n] = mfma32(v0, ph8[n][0], Oa[dt][n]);
                Oa[dt][n] = mfma32(v1, ph8[n][1], Oa[dt][n]);
            }
        }

        if (pre) __syncthreads();   // drains own DMA; all waves done with pp
    };

    for (int kt = 0; kt < 32; kt += 2) {
        tile(kt,     0, biasA, biasB);
        tile(kt + 1, 1, biasB, biasA);
    }

    // ---- epilogue: O^T -> bf16 hi/lo o-planes (B,N,D) ----
#pragma unroll
    for (int n = 0; n < 2; n++) {
        const float inv = 1.0f / liacc[n][0];
        const size_t row = (size_t)b*2048 + qb + n*16 + col;
#pragma unroll
        for (int dt = 0; dt < 4; dt++) {
            s4v hv, lv;
#pragma unroll
            for (int r = 0; r < 4; r++) {
                float y = Oa[dt][n][r] * inv;
                unsigned short hb = f2bf(y);
                hv[r] = (short)hb;
                union { float f; unsigned u; } rr; rr.f = y - bf2f(hb);
                lv[r] = (short)(rr.u >> 16);
            }
            const size_t o = row*1024 + h*64 + dt*16 + quad*4;
            *(s4v*)&Oh[o] = hv;
            *(s4v*)&Ol[o] = lv;
        }
    }
}

// ---------------------------------------------------------------------------
extern "C" void kernel_launch(void* const* d_in, const int* in_sizes, int n_in,
                              void* d_out, int out_size, void* d_ws, size_t ws_size,
                              hipStream_t stream)
{
    const float* x    = (const float*)d_in[0];
    const float* cm   = (const float*)d_in[1];
    const float* im   = (const float*)d_in[2];
    const float* Wqkv = (const float*)d_in[3];
    const float* Wout = (const float*)d_in[4];
    const float* qw   = (const float*)d_in[5];
    const float* kw   = (const float*)d_in[6];
    const float* gate = (const float*)d_in[7];
    float* out = (float*)d_out;

    // ---- workspace layout (bytes) ----
    char* ws = (char*)d_ws;
    short* qhp = (short*)(ws);                    // 8.39 MB each
    short* qlp = (short*)(ws +  8388608);
    short* khp = (short*)(ws + 16777216);
    short* klp = (short*)(ws + 25165824);
    short* vp  = (short*)(ws + 33554432);         // V^T[b,h,d,n'] bf16 (sigma)
    short* oh  = (short*)(ws + 41943040);
    short* ol  = (short*)(ws + 50331648);
    short* woh = (short*)(ws + 58720256);         // 2.10 MB each
    short* wol = (short*)(ws + 60817408);
    float* rsb = (float*)(ws + 62914560);         // 16 KB
    char*  U   = ws + 62930944;                   // union region
    short* xh  = (short*)(U);                     // 8.39 MB (dead after gemm0)
    short* xl  = (short*)(U +  8388608);
    short* wqh = (short*)(U + 16777216);          // 6.29 MB
    short* wql = (short*)(U + 23068672);
    float* bias2 = (float*)(U);                   // 33.55 MB (after gemm0)

    static bool lds_init = false;
    if (!lds_init) {
        hipFuncSetAttribute((const void*)gemm_qkv,
                            hipFuncAttributeMaxDynamicSharedMemorySize, 131072);
        lds_init = true;
    }

    // 1) split inputs into bf16 hi/lo planes
    planes_k<<<4096, 256, 0, stream>>>(x,    xh,  xl);
    planes_k<<<3072, 256, 0, stream>>>(Wqkv, wqh, wql);
    planes_k<<<1024, 256, 0, stream>>>(Wout, woh, wol);
    // 2) qkv projection (256^2 dbuf MFMA) + fused rmsnorm -> planes, v^T
    gemm_qkv<<<dim3(12, 16), 512, 131072, stream>>>(xh, xl, wqh, wql,
        qhp, qlp, khp, klp, vp, qw, kw);
    // 3) bias precompute (overwrites x/wq plane region — dead after gemm0)
    rowscale_k<<<64, 256, 0, stream>>>(cm, rsb);
    bias_pre<<<256, 256, 0, stream>>>(cm, im, rsb, bias2);
    // 4) flash attention -> bf16 o-planes  (512 blocks = 2/CU, q-tile 128)
    attn_mfma<<<512, 256, 0, stream>>>(qhp, qlp, khp, klp, vp, bias2, gate,
                                       oh, ol);
    // 5) output projection (MFMA, 64-row tiles -> 512 blocks) -> fp32 out
    gemm_out<64><<<dim3(8, 64), 256, 0, stream>>>(oh, ol, woh, wol, out);
}

// Round 5
// 350.974 us; speedup vs baseline: 1.1230x; 1.0015x over previous
//
#include <hip/hip_runtime.h>
#include <math.h>

// Problem constants: B=2, N=2048, D=1024, H=16, HD=64, C=4

typedef __attribute__((ext_vector_type(8))) short s8v;
typedef __attribute__((ext_vector_type(4))) short s4v;
typedef __attribute__((ext_vector_type(4))) float f4v;

#define L2E 1.44269504088896340736f

__device__ __forceinline__ unsigned short f2bf(float x) {
    union { float f; unsigned u; } v; v.f = x;
    unsigned r = v.u + 0x7FFF + ((v.u >> 16) & 1);
    return (unsigned short)(r >> 16);
}
__device__ __forceinline__ float bf2f(unsigned short h) {
    union { unsigned u; float f; } v; v.u = ((unsigned)h) << 16;
    return v.f;
}
__device__ __forceinline__ f4v mfma32(s8v a, s8v b, f4v c) {
    return __builtin_amdgcn_mfma_f32_16x16x32_bf16(a, b, c, 0, 0, 0);
}
__device__ __forceinline__ void gl_lds16(const void* g, void* l) {
    __builtin_amdgcn_global_load_lds(
        (const __attribute__((address_space(1))) unsigned*)g,
        (__attribute__((address_space(3))) unsigned*)l, 16, 0, 0);
}
// raw v_exp_f32: 1 instr, no OCML range-fixup wrapper
__device__ __forceinline__ float exp2g(float x) {
    float r; asm("v_exp_f32 %0, %1" : "=v"(r) : "v"(x)); return r;
}

// ---------------------------------------------------------------------------
// Split fp32 tensor into bf16 hi/lo planes.
// ---------------------------------------------------------------------------
__global__ __launch_bounds__(256)
void planes_k(const float* __restrict__ src, short* __restrict__ ph,
              short* __restrict__ pl)
{
    const int i = blockIdx.x * 256 + threadIdx.x;
    float4 f = ((const float4*)src)[i];
    float fa[4] = {f.x, f.y, f.z, f.w};
    s4v h4, l4;
#pragma unroll
    for (int j = 0; j < 4; j++) {
        unsigned short hb = f2bf(fa[j]);
        h4[j] = (short)hb;
        l4[j] = (short)f2bf(fa[j] - bf2f(hb));
    }
    ((s4v*)ph)[i] = h4;
    ((s4v*)pl)[i] = l4;
}

// ---------------------------------------------------------------------------
// Persistent-tile GEMM  C[M,NC] = A[M,1024]*B[NC,1024]^T, 3-term bf16 hi/lo.
// 128x128 tiles, BK=32, 512 threads (8 waves, wave tile 32x64), DOUBLE-
// BUFFERED LDS (64 KB dynamic), ONE barrier per K-step.  Grid = exactly 256
// blocks (1/CU); each block processes NT tiles (tile id = bid + rep*256, so
// the A row-panel is fixed per block -> L2/XCD locality).  Next tile's first
// DMA is issued BEFORE the epilogue so its latency hides under it.
// MODE 0 (NT=3, N=3072): fused RMSNorm (q pre-scaled by 0.125*log2(e)),
//   scatter to q/k hi/lo planes + sigma-permuted V^T.
// MODE 1 (NT=1, N=1024): plain fp32 row-major Cout.
// ---------------------------------------------------------------------------
template<int MODE, int NT>
__global__ __launch_bounds__(512, 2)
void gemm2(const short* __restrict__ Ah, const short* __restrict__ Al,
           const short* __restrict__ Bh, const short* __restrict__ Bl,
           short* __restrict__ Qhp, short* __restrict__ Qlp,
           short* __restrict__ Khp, short* __restrict__ Klp,
           short* __restrict__ Vp, float* __restrict__ Cout,
           const float* __restrict__ qw, const float* __restrict__ kw)
{
    extern __shared__ short L[];            // 32768 shorts = 64 KB
    short* sAh = L;                          // [2][4096] each plane
    short* sAl = L + 8192;
    short* sBh = L + 16384;
    short* sBl = L + 24576;

    const int t = threadIdx.x, w = t >> 6, lane = t & 63;
    const int col = lane & 15, quad = lane >> 4;
    const int wm = w >> 1;                   // 0..3 -> 32-row band
    const int wn = w & 1;                    // 0..1 -> 64-col half

    // staging: thread t handles row srow=t>>2, 16B chunk (t&3), source-side
    // XOR swizzle by row&3 (matches fragment-read swizzle).
    const int srow = t >> 2;
    const int sko  = ((t & 3) ^ (srow & 3)) * 8;
    const int sdst = t * 8;                  // shorts; = wave base + lane*16B

    int tid = blockIdx.x;
    int m0 = (tid & 31) * 128, n0 = (tid >> 5) * 128;
    const short* agh = Ah + (size_t)(m0 + srow)*1024 + sko;
    const short* agl = Al + (size_t)(m0 + srow)*1024 + sko;
    const short* bgh = Bh + (size_t)(n0 + srow)*1024 + sko;
    const short* bgl = Bl + (size_t)(n0 + srow)*1024 + sko;

    auto stage = [&](int k0, int pp) {
        gl_lds16(agh + k0, &sAh[pp*4096 + sdst]);
        gl_lds16(agl + k0, &sAl[pp*4096 + sdst]);
        gl_lds16(bgh + k0, &sBh[pp*4096 + sdst]);
        gl_lds16(bgl + k0, &sBl[pp*4096 + sdst]);
    };
    stage(0, 0);

    for (int rep = 0; rep < NT; rep++) {
        __syncthreads();                     // drains this tile's k0 stage

        f4v acc[2][4];
#pragma unroll
        for (int i = 0; i < 2; i++)
#pragma unroll
            for (int j = 0; j < 4; j++) { f4v z = {0.f,0.f,0.f,0.f}; acc[i][j] = z; }

        for (int kt = 0; kt < 32; kt++) {
            const int pp = kt & 1;
            if (kt < 31) stage((kt + 1) * 32, pp ^ 1);

            const int swz = ((quad ^ (col & 3)) << 3);
            s8v bhf[4], blf[4];
#pragma unroll
            for (int j = 0; j < 4; j++) {
                const int boff = pp*4096 + (wn*64 + j*16 + col)*32 + swz;
                bhf[j] = *(const s8v*)&sBh[boff];
                blf[j] = *(const s8v*)&sBl[boff];
            }
#pragma unroll
            for (int i = 0; i < 2; i++) {
                const int aoff = pp*4096 + (wm*32 + i*16 + col)*32 + swz;
                s8v ah = *(const s8v*)&sAh[aoff];
                s8v al = *(const s8v*)&sAl[aoff];
#pragma unroll
                for (int j = 0; j < 4; j++) {
                    acc[i][j] = mfma32(ah, bhf[j], acc[i][j]);
                    acc[i][j] = mfma32(ah, blf[j], acc[i][j]);
                    acc[i][j] = mfma32(al, bhf[j], acc[i][j]);
                }
            }
            __syncthreads();                 // drains DMA; all reads of pp done
        }

        const int em0 = m0, en0 = n0;
        if (rep + 1 < NT) {
            tid = blockIdx.x + (rep + 1) * 256;
            m0 = (tid & 31) * 128; n0 = (tid >> 5) * 128;
            agh = Ah + (size_t)(m0 + srow)*1024 + sko;
            agl = Al + (size_t)(m0 + srow)*1024 + sko;
            bgh = Bh + (size_t)(n0 + srow)*1024 + sko;
            bgl = Bl + (size_t)(n0 + srow)*1024 + sko;
            stage(0, 0);                     // DMA overlaps the epilogue below
        }

        if (MODE == 0) {
            // fused RMSNorm over HD=64 (wave covers exactly one 64-col head)
            const int whichW = (en0 + wn*64) >> 10;    // wave-uniform 0=q,1=k,2=v
            if (whichW < 2) {
                const float* nw = (whichW == 0) ? qw : kw;
                const float sfac = (whichW == 0) ? (0.125f * L2E) : 1.0f;
                float wj[4];
#pragma unroll
                for (int j = 0; j < 4; j++) wj[j] = nw[j*16 + col] * sfac;
#pragma unroll
                for (int i = 0; i < 2; i++)
#pragma unroll
                for (int r = 0; r < 4; r++) {
                    float s2 = acc[i][0][r]*acc[i][0][r] + acc[i][1][r]*acc[i][1][r]
                             + acc[i][2][r]*acc[i][2][r] + acc[i][3][r]*acc[i][3][r];
                    s2 += __shfl_xor(s2, 1);
                    s2 += __shfl_xor(s2, 2);
                    s2 += __shfl_xor(s2, 4);
                    s2 += __shfl_xor(s2, 8);
                    const float scn = rsqrtf(s2*(1.0f/64.0f) + 1e-6f);
#pragma unroll
                    for (int j = 0; j < 4; j++) acc[i][j][r] *= scn*wj[j];
                }
            }
#pragma unroll
            for (int i = 0; i < 2; i++)
#pragma unroll
            for (int j = 0; j < 4; j++) {
                const int gcol = en0 + wn*64 + j*16 + col;
                const int which = gcol >> 10;          // wave-uniform
                const int hh = (gcol >> 6) & 15;
                const int hd = gcol & 63;
                const int grow0 = em0 + wm*32 + i*16 + quad*4;
                const int b = grow0 >> 11, nn0 = grow0 & 2047;
                if (which == 2) {
                    // V^T[b,h,d,n'] bf16, sigma key permutation in 64-block
                    s4v hv;
#pragma unroll
                    for (int r = 0; r < 4; r++) hv[r] = (short)f2bf(acc[i][j][r]);
                    const int nswz = (nn0 & ~60) | ((nn0 & 12) << 2) | ((nn0 & 48) >> 2);
                    *(s4v*)&Vp[((size_t)(b*16 + hh)*64 + hd)*2048 + nswz] = hv;
                } else {
                    short* Hp = (which == 0) ? Qhp : Khp;
                    short* Lp = (which == 0) ? Qlp : Klp;
                    const size_t base = ((size_t)(b*16 + hh)*2048 + nn0)*64 + hd;
#pragma unroll
                    for (int r = 0; r < 4; r++) {
                        const float v = acc[i][j][r];
                        const unsigned short hb = f2bf(v);
                        union { float f; unsigned u; } rr; rr.f = v - bf2f(hb);
                        Hp[base + (size_t)r*64] = (short)hb;
                        Lp[base + (size_t)r*64] = (short)(rr.u >> 16);
                    }
                }
            }
        } else {
#pragma unroll
            for (int i = 0; i < 2; i++)
#pragma unroll
            for (int j = 0; j < 4; j++) {
                const int gcol = en0 + wn*64 + j*16 + col;
#pragma unroll
                for (int r = 0; r < 4; r++) {
                    const int grow = em0 + wm*32 + i*16 + quad*4 + r;
                    Cout[(size_t)grow*1024 + gcol] = acc[i][j][r];
                }
            }
        }
    }
}

// ---------------------------------------------------------------------------
// rowscale[b,q] = 1 / max(max_k dot4(cm[b,:,q], cm[b,:,k]), 1e-6)
// ---------------------------------------------------------------------------
__global__ __launch_bounds__(256)
void rowscale_k(const float* __restrict__ cm, float* __restrict__ rs)
{
    __shared__ float cms[4][2048];
    const int b  = blockIdx.x >> 5;
    const int qt = blockIdx.x & 31;
    const float* base = cm + (size_t)b * 4 * 2048;
    for (int i = threadIdx.x; i < 2048; i += 256) {
        cms[0][i] = base[i];
        cms[1][i] = base[2048 + i];
        cms[2][i] = base[4096 + i];
        cms[3][i] = base[6144 + i];
    }
    __syncthreads();
    const int q    = qt * 64 + (threadIdx.x >> 2);
    const int part = threadIdx.x & 3;
    const float a0 = cms[0][q], a1 = cms[1][q], a2 = cms[2][q], a3 = cms[3][q];
    float mx = 0.f;
    for (int i = 0; i < 512; i++) {
        const int k = part + 4 * i;
        float d = a0*cms[0][k] + a1*cms[1][k] + a2*cms[2][k] + a3*cms[3][k];
        mx = fmaxf(mx, d);
    }
    mx = fmaxf(mx, __shfl_xor(mx, 1));
    mx = fmaxf(mx, __shfl_xor(mx, 2));
    if (part == 0) rs[b * 2048 + q] = 1.0f / fmaxf(mx, 1e-6f);
}

// ---------------------------------------------------------------------------
// Bias precompute, pre-scaled by 3*log2(e) (gate applied in attn):
//  Bias2[b][k>>2][q][k&3] = ((dot4*rsq - 0.5)*2 + 0.3*im) * 3*L2E
// 1024 blocks (4/CU) for latency hiding.
// ---------------------------------------------------------------------------
__global__ __launch_bounds__(256)
void bias_pre(const float* __restrict__ cm, const float* __restrict__ im,
              const float* __restrict__ rs, float* __restrict__ Bias2)
{
    const int bid = blockIdx.x;
    const int qq = bid & 15;
    const int kt = (bid >> 4) & 31;
    const int b  = bid >> 9;

    __shared__ float cmk[4][64];
    const int t = threadIdx.x;
    const int k0 = kt * 64;
    cmk[t >> 6][t & 63] = cm[(size_t)b*8192 + (t >> 6)*2048 + k0 + (t & 63)];
    __syncthreads();

    const int klane = t & 15;
    const int qrow  = t >> 4;
    const int kk = k0 + klane*4;
    const int kg = kk >> 2;
    float ck[4][4];
#pragma unroll
    for (int c = 0; c < 4; c++)
#pragma unroll
        for (int j = 0; j < 4; j++) ck[c][j] = cmk[c][klane*4 + j];

    const float* cmb = cm + (size_t)b * 8192;
    const float kS = 3.0f * L2E;
    for (int it = 0; it < 8; it++) {
        const int q = qq*128 + it*16 + qrow;
        float4 imv = *(const float4*)(im + ((size_t)b*2048 + q)*2048 + kk);
        const float rsq = rs[b*2048 + q];
        const float c0 = cmb[q], c1 = cmb[2048+q], c2 = cmb[4096+q], c3 = cmb[6144+q];
        float o[4];
        float iv[4] = {imv.x, imv.y, imv.z, imv.w};
#pragma unroll
        for (int j = 0; j < 4; j++) {
            float same = c0*ck[0][j] + c1*ck[1][j] + c2*ck[2][j] + c3*ck[3][j];
            o[j] = ((same*rsq - 0.5f)*2.0f + 0.3f*iv[j]) * kS;
        }
        *(float4*)(Bias2 + (((size_t)b*512 + kg)*2048 + q)*4) =
            make_float4(o[0], o[1], o[2], o[3]);
    }
}

// ---------------------------------------------------------------------------
// Flash attention, S^T orientation.  q-tile 128 (32 q/wave), 512 blocks,
// 2 blocks/CU.  K AND V staged by global_load_lds DMA (double-buffered,
// XOR source swizzle); V arrives sigma-permuted+pre-transposed so PV runs
// as 16x16x32 MFMA with conflict-free b128 LDS reads and zero shuffles.
// li accumulated by MFMA (ones-vector row-sum).  One barrier per tile.
// Softmax: NO-MAX (scores provably bounded |sr|<=17.2 by RMSNorm
// Cauchy-Schwarz + bias bound; exp2 range-safe in bf16).
// ---------------------------------------------------------------------------
__global__ __launch_bounds__(256, 2)
void attn_mfma(const short* __restrict__ Qhp, const short* __restrict__ Qlp,
               const short* __restrict__ Khg, const short* __restrict__ Klg,
               const short* __restrict__ VtG, const float* __restrict__ Bias2,
               const float* __restrict__ gate, short* __restrict__ Oh,
               short* __restrict__ Ol)
{
    const int bid = blockIdx.x;
    const int h  = bid & 15;
    const int qt = (bid >> 4) & 15;
    const int b  = bid >> 8;

    __shared__ __align__(16) short Kbuf[2][2][64*64];   // [pp][hi/lo][key][d] swz
    __shared__ __align__(16) short Vbuf[2][64*64];      // [pp][d][sigma-key swz]

    const int t    = threadIdx.x;
    const int w    = t >> 6;
    const int lane = t & 63;
    const int col  = lane & 15;
    const int quad = lane >> 4;

    const size_t headoff = ((size_t)(b*16 + h)) * 2048 * 64;
    const int qb = qt*128 + w*32;

    // ---- Q B-fragments (hi/lo) straight from planes (q pre-scaled) ----
    s8v qfh[2][2], qfl[2][2];
#pragma unroll
    for (int n = 0; n < 2; n++)
#pragma unroll
    for (int c = 0; c < 2; c++) {
        const size_t off = headoff + (size_t)(qb + n*16 + col)*64 + c*32 + quad*8;
        qfh[n][c] = *(const s8v*)(Qhp + off);
        qfl[n][c] = *(const s8v*)(Qlp + off);
    }

    const float g = fminf(fmaxf(gate[h], 0.f), 1.f);

    s8v ones8;
#pragma unroll
    for (int j = 0; j < 8; j++) ones8[j] = (short)0x3F80;   // bf16 1.0

    f4v liacc[2];
    f4v Oa[4][2];
    {
        f4v z = {0.f,0.f,0.f,0.f};
        liacc[0] = z; liacc[1] = z;
#pragma unroll
        for (int dt = 0; dt < 4; dt++)
#pragma unroll
            for (int n = 0; n < 2; n++) Oa[dt][n] = z;
    }

    // ---- staging bases ----
    const short* ksrc_h = Khg + headoff + (size_t)(w*8 + (lane>>3))*64
                          + ((lane&7) ^ (lane>>3))*8;
    const short* ksrc_l = Klg + headoff + (size_t)(w*8 + (lane>>3))*64
                          + ((lane&7) ^ (lane>>3))*8;
    // V^T rows: d = cc*32 + w*8 + (lane>>3); sigma-key-group XOR by d&7
    const short* vsrcT = VtG + headoff + (size_t)(w*8 + (lane>>3))*2048
                          + ((lane&7) ^ (lane>>3))*8;

    const float* bptr[2];
#pragma unroll
    for (int n = 0; n < 2; n++)
        bptr[n] = Bias2 + (((size_t)b*512 + quad)*2048 + qb + n*16 + col)*4;

    auto dma = [&](int kbase, int pp) {
#pragma unroll
        for (int j = 0; j < 2; j++) {
            gl_lds16(ksrc_h + (size_t)kbase*64 + j*2048, &Kbuf[pp][0][(j*4 + w)*512]);
            gl_lds16(ksrc_l + (size_t)kbase*64 + j*2048, &Kbuf[pp][1][(j*4 + w)*512]);
        }
#pragma unroll
        for (int cc = 0; cc < 2; cc++)
            gl_lds16(vsrcT + (size_t)(kbase + cc*65536), &Vbuf[pp][cc*2048 + w*512]);
    };

    float4 biasA[4][2], biasB[4][2];

    // ---- prologue: tile 0 ----
    dma(0, 0);
#pragma unroll
    for (int s = 0; s < 4; s++)
#pragma unroll
    for (int n = 0; n < 2; n++)
        biasA[s][n] = *(const float4*)(bptr[n] + (size_t)s*4*8192);
    __syncthreads();

    auto tile = [&](int kt, int pp, float4 (&BC)[4][2], float4 (&BN)[4][2]) {
        const int kbase = kt * 64;
        const bool pre = kt < 31;
        if (pre) {
            dma(kbase + 64, pp ^ 1);
#pragma unroll
            for (int s = 0; s < 4; s++)
#pragma unroll
            for (int n = 0; n < 2; n++)
                BN[s][n] = *(const float4*)(bptr[n] +
                    ((size_t)((kbase >> 2) + 16) + s*4)*8192);
        }

        // ---- S^T = K·Q^T (3-term hi/lo), scales pre-folded ----
        f4v S[4][2];
#pragma unroll
        for (int s = 0; s < 4; s++)
#pragma unroll
            for (int n = 0; n < 2; n++) { f4v z = {0.f,0.f,0.f,0.f}; S[s][n] = z; }
#pragma unroll
        for (int s = 0; s < 4; s++)
#pragma unroll
        for (int c = 0; c < 2; c++) {
            const int koff = (s*16 + col)*64 + (((c*4 + quad) ^ (col & 7)) << 3);
            s8v kh = *(const s8v*)&Kbuf[pp][0][koff];
            s8v kl = *(const s8v*)&Kbuf[pp][1][koff];
#pragma unroll
            for (int n = 0; n < 2; n++) {
                S[s][n] = mfma32(kh, qfh[n][c], S[s][n]);
                S[s][n] = mfma32(kh, qfl[n][c], S[s][n]);
                S[s][n] = mfma32(kl, qfh[n][c], S[s][n]);
            }
        }

        // ---- bias (1 FMA) + no-max softmax: p = exp2(S + g*bias) ----
        s8v ph8[2][2];
#pragma unroll
        for (int n = 0; n < 2; n++) {
            union { unsigned uu[4]; s8v v; } pk0, pk1;
#pragma unroll
            for (int s = 0; s < 4; s++) {
                const float bb[4] = {BC[s][n].x, BC[s][n].y, BC[s][n].z, BC[s][n].w};
                const float p0 = exp2g(fmaf(bb[0], g, S[s][n][0]));
                const float p1 = exp2g(fmaf(bb[1], g, S[s][n][1]));
                const float p2 = exp2g(fmaf(bb[2], g, S[s][n][2]));
                const float p3 = exp2g(fmaf(bb[3], g, S[s][n][3]));
                unsigned u01, u23;
                asm("v_cvt_pk_bf16_f32 %0, %1, %2" : "=v"(u01) : "v"(p0), "v"(p1));
                asm("v_cvt_pk_bf16_f32 %0, %1, %2" : "=v"(u23) : "v"(p2), "v"(p3));
                if (s < 2) { pk0.uu[s*2] = u01;     pk0.uu[s*2 + 1] = u23; }
                else       { pk1.uu[(s-2)*2] = u01; pk1.uu[(s-2)*2 + 1] = u23; }
            }
            ph8[n][0] = pk0.v;
            ph8[n][1] = pk1.v;
        }

        // ---- li row-sum by MFMA (rows of C identical; only [0] consumed) ----
#pragma unroll
        for (int n = 0; n < 2; n++)
#pragma unroll
        for (int m = 0; m < 2; m++)
            liacc[n] = mfma32(ones8, ph8[n][m], liacc[n]);

        // ---- O^T += V^T·P^T  (16x16x32, conflict-free b128 V reads) ----
#pragma unroll
        for (int dt = 0; dt < 4; dt++) {
            const int vrow = (dt*16 + col)*64;
            s8v v0 = *(const s8v*)&Vbuf[pp][vrow + ((((quad*2)    ) ^ (col & 7)) << 3)];
            s8v v1 = *(const s8v*)&Vbuf[pp][vrow + ((((quad*2) + 1) ^ (col & 7)) << 3)];
#pragma unroll
            for (int n = 0; n < 2; n++) {
                Oa[dt][n] = mfma32(v0, ph8[n][0], Oa[dt][n]);
                Oa[dt][n] = mfma32(v1, ph8[n][1], Oa[dt][n]);
            }
        }

        if (pre) __syncthreads();   // drains own DMA; all waves done with pp
    };

    for (int kt = 0; kt < 32; kt += 2) {
        tile(kt,     0, biasA, biasB);
        tile(kt + 1, 1, biasB, biasA);
    }

    // ---- epilogue: O^T -> bf16 hi/lo o-planes (B,N,D) ----
#pragma unroll
    for (int n = 0; n < 2; n++) {
        const float inv = 1.0f / liacc[n][0];
        const size_t row = (size_t)b*2048 + qb + n*16 + col;
#pragma unroll
        for (int dt = 0; dt < 4; dt++) {
            s4v hv, lv;
#pragma unroll
            for (int r = 0; r < 4; r++) {
                float y = Oa[dt][n][r] * inv;
                unsigned short hb = f2bf(y);
                hv[r] = (short)hb;
                union { float f; unsigned u; } rr; rr.f = y - bf2f(hb);
                lv[r] = (short)(rr.u >> 16);
            }
            const size_t o = row*1024 + h*64 + dt*16 + quad*4;
            *(s4v*)&Oh[o] = hv;
            *(s4v*)&Ol[o] = lv;
        }
    }
}

// ---------------------------------------------------------------------------
extern "C" void kernel_launch(void* const* d_in, const int* in_sizes, int n_in,
                              void* d_out, int out_size, void* d_ws, size_t ws_size,
                              hipStream_t stream)
{
    const float* x    = (const float*)d_in[0];
    const float* cm   = (const float*)d_in[1];
    const float* im   = (const float*)d_in[2];
    const float* Wqkv = (const float*)d_in[3];
    const float* Wout = (const float*)d_in[4];
    const float* qw   = (const float*)d_in[5];
    const float* kw   = (const float*)d_in[6];
    const float* gate = (const float*)d_in[7];
    float* out = (float*)d_out;

    // ---- workspace layout (bytes) ----
    char* ws = (char*)d_ws;
    short* qhp = (short*)(ws);                    // 8.39 MB each
    short* qlp = (short*)(ws +  8388608);
    short* khp = (short*)(ws + 16777216);
    short* klp = (short*)(ws + 25165824);
    short* vp  = (short*)(ws + 33554432);         // V^T[b,h,d,n'] bf16 (sigma)
    short* oh  = (short*)(ws + 41943040);
    short* ol  = (short*)(ws + 50331648);
    short* woh = (short*)(ws + 58720256);         // 2.10 MB each
    short* wol = (short*)(ws + 60817408);
    float* rsb = (float*)(ws + 62914560);         // 16 KB
    char*  U   = ws + 62930944;                   // union region
    short* xh  = (short*)(U);                     // 8.39 MB (dead after gemm0)
    short* xl  = (short*)(U +  8388608);
    short* wqh = (short*)(U + 16777216);          // 6.29 MB
    short* wql = (short*)(U + 23068672);
    float* bias2 = (float*)(U);                   // 33.55 MB (after gemm0)

    static bool lds_init = false;
    if (!lds_init) {
        hipFuncSetAttribute((const void*)&gemm2<0,3>,
                            hipFuncAttributeMaxDynamicSharedMemorySize, 65536);
        hipFuncSetAttribute((const void*)&gemm2<1,1>,
                            hipFuncAttributeMaxDynamicSharedMemorySize, 65536);
        lds_init = true;
    }

    // 1) split inputs into bf16 hi/lo planes
    planes_k<<<4096, 256, 0, stream>>>(x,    xh,  xl);
    planes_k<<<3072, 256, 0, stream>>>(Wqkv, wqh, wql);
    planes_k<<<1024, 256, 0, stream>>>(Wout, woh, wol);
    // 2) qkv projection: persistent 256 blocks x 3 tiles (768 x 128^2 tiles)
    gemm2<0,3><<<256, 512, 65536, stream>>>(xh, xl, wqh, wql,
        qhp, qlp, khp, klp, vp, nullptr, qw, kw);
    // 3) bias precompute (overwrites x/wq plane region — dead after gemm0)
    rowscale_k<<<64, 256, 0, stream>>>(cm, rsb);
    bias_pre<<<1024, 256, 0, stream>>>(cm, im, rsb, bias2);
    // 4) flash attention -> bf16 o-planes  (512 blocks = 2/CU, q-tile 128)
    attn_mfma<<<512, 256, 0, stream>>>(qhp, qlp, khp, klp, vp, bias2, gate,
                                       oh, ol);
    // 5) output projection: 256 blocks x 1 tile (256 x 128^2 tiles) -> fp32
    gemm2<1,1><<<256, 512, 65536, stream>>>(oh, ol, woh, wol,
        nullptr, nullptr, nullptr, nullptr, nullptr, out, nullptr, nullptr);
}